// Round 12
// baseline (1034.154 us; speedup 1.0000x reference)
//
#include <hip/hip_runtime.h>
#include <hip/hip_bf16.h>

#define B_ 16
#define T_ 64
#define E_ 512
#define H_ 512
#define V_ 32000

typedef __attribute__((ext_vector_type(4))) float f32x4;
typedef __attribute__((ext_vector_type(8))) short s16x8;

__device__ __forceinline__ float sigm(float x){ return 1.0f/(1.0f + __expf(-x)); }

__device__ __forceinline__ unsigned short f2bf(float x){
  unsigned int u = __float_as_uint(x);
  return (unsigned short)((u + 0x7FFFu + ((u>>16)&1u)) >> 16);
}

// ---- coherence-point ops (no cache-wide writeback/invalidate anywhere) ----
__device__ __forceinline__ unsigned load_coh(const unsigned* p){
  unsigned v;
  asm volatile("global_load_dword %0, %1, off sc0 sc1\n\ts_waitcnt vmcnt(0)"
               : "=v"(v) : "v"(p) : "memory");
  return v;
}
__device__ __forceinline__ void store_coh16(unsigned short* p, unsigned v){
  asm volatile("global_store_short %0, %1, off sc0 sc1" :: "v"(p), "v"(v) : "memory");
}
__device__ __forceinline__ void store_cohf(float* p, float v){
  asm volatile("global_store_dword %0, %1, off sc0 sc1" :: "v"(p), "v"(v) : "memory");
}
__device__ __forceinline__ void store_cohu(unsigned* p, unsigned v){
  asm volatile("global_store_dword %0, %1, off sc0 sc1" :: "v"(p), "v"(v) : "memory");
}

// ---- grid barrier: RMW-free flags + detector; gen sharded on 8 lines ------
__device__ __forceinline__ void gbar3(unsigned* barb, unsigned bi1, int nblk,
                                      bool det, int myblk){
  asm volatile("s_waitcnt vmcnt(0)" ::: "memory");
  __syncthreads();
  const int tid = threadIdx.x;
  if(tid == 0) store_cohu(barb + (size_t)myblk*16, bi1);
  if(det){
    if(tid < nblk){
      const unsigned* fp = barb + (size_t)tid*16;
      while(load_coh(fp) < bi1) __builtin_amdgcn_s_sleep(1);
    }
    __syncthreads();
    if(tid < 8) store_cohu(barb + 4096 + (size_t)tid*16, bi1);
  } else {
    if(tid == 0){
      const unsigned* gp = barb + 4096 + (size_t)(myblk & 7)*16;
      while(load_coh(gp) < bi1) __builtin_amdgcn_s_sleep(1);
    }
  }
  __syncthreads();
}

__global__ void k_barinit(unsigned* bar){
  int i = blockIdx.x*256 + threadIdx.x;
  if(i < 16384) bar[i] = 0u;
}

// ------------- embedding gather -> bf16 ------------------------------------
__global__ void k_gather(const int* __restrict__ ids, const float* __restrict__ emb,
                         unsigned short* __restrict__ out){
  const int row = blockIdx.x;
  const int id  = ids[row];
  float4 v = *(const float4*)(emb + (size_t)id*E_ + threadIdx.x*4);
  ushort4 o;
  o.x = f2bf(v.x); o.y = f2bf(v.y); o.z = f2bf(v.z); o.w = f2bf(v.w);
  *(ushort4*)(out + (size_t)row*E_ + threadIdx.x*4) = o;
}

// ------------- transpose+convert(+permute)(+swizzle), device version -------
__device__ __forceinline__ void tcvt_dev(const float* __restrict__ in,
    unsigned short* __restrict__ out, int N, int Hp, int Kfull, int koff, int swz,
    int bx, int by, float (*tile)[33]){
  const int n0 = bx*32, k0 = by*32;
  const int x = threadIdx.x & 31, y = threadIdx.x >> 5;
  __syncthreads();
  #pragma unroll
  for(int i=0;i<4;i++){
    int k = y + i*8;
    tile[k][x] = in[(size_t)(k0+k)*N + n0 + x];
  }
  __syncthreads();
  #pragma unroll
  for(int i=0;i<4;i++){
    int nl = y + i*8;
    int n  = n0 + nl;
    int p  = Hp ? ((n % Hp)*4 + n / Hp) : n;
    int kk = koff + k0 + x;
    size_t idx;
    if(swz){
      int k2 = kk*2;
      int slot = ((k2>>4)&7) ^ (p&7);
      idx = (size_t)p*Kfull + (((k2 & ~127) | (slot<<4) | (k2 & 15)) >> 1);
    } else {
      idx = (size_t)p*Kfull + kk;
    }
    out[idx] = f2bf(tile[x][nl]);
  }
}

__global__ __launch_bounds__(256)
void k_tcvt(const float* __restrict__ in, unsigned short* __restrict__ out,
            int N, int Hp, int Kfull, int koff, int swz){
  __shared__ float tile[32][33];
  tcvt_dev(in, out, N, Hp, Kfull, koff, swz, blockIdx.x, blockIdx.y, tile);
}

// ------------- bias permute -------------------------------------------------
__global__ void k_bpack(const float* __restrict__ b, float* __restrict__ out, int H, int N){
  int p = blockIdx.x*256 + threadIdx.x;
  if(p < N) out[p] = b[(p&3)*H + (p>>2)];
}

// ------------- init states --------------------------------------------------
__global__ void k_init1(const float* __restrict__ init_state,
                        unsigned short* h0i, float* c0i, unsigned short* h1i, float* c1i){
  int i = blockIdx.x*256 + threadIdx.x;
  if(i >= B_*H_) return;
  float v0 = init_state[i];
  float v1 = init_state[B_*H_ + i];
  h0i[i] = f2bf(v0); c0i[i] = v0;
  h1i[i] = f2bf(v1); c1i[i] = v1;
}

// h0seq1/h1seq1 are T-MAJOR ([t*B+b]) — final row at t=63.
__global__ void k_init2(const float* __restrict__ init_state,
                        const unsigned short* __restrict__ h0seq1,
                        const unsigned short* __restrict__ h1seq1,
                        const float* __restrict__ c0f1, const float* __restrict__ c1f1,
                        unsigned short* h20i, unsigned short* h21i,
                        float* c20i, float* c21i){
  const int l = blockIdx.y;
  int i = blockIdx.x*256 + threadIdx.x;
  if(i >= B_*2*H_) return;
  const int r = i >> 10, j = i & 1023;
  unsigned short* ho = l ? h21i : h20i;
  float* co = l ? c21i : c20i;
  if(j < H_){
    float v = init_state[(size_t)l*B_*H_ + r*H_ + j];
    ho[i] = f2bf(v); co[i] = v;
  } else {
    const unsigned short* hs = l ? h1seq1 : h0seq1;
    const float* cf = l ? c1f1 : c0f1;
    ho[i] = hs[(size_t)((T_-1)*B_ + r)*H_ + (j - H_)];
    co[i] = cf[r*H_ + (j - H_)];
  }
}

// ------------- MFMA GEMM tile (B pre-transposed bf16); optional row remap --
__device__ __forceinline__ void mm_tile(const unsigned short* __restrict__ A,
    const unsigned short* __restrict__ Bt, const float* __restrict__ bias,
    float* __restrict__ C, int N, int K, int bm, int bn,
    unsigned short* As, unsigned short* Bs, int remap){
  const int tid = threadIdx.x;
  const int lane = tid & 63, w = tid >> 6;
  const int wm = (w>>1)*64, wn = (w&1)*64;
  const int l15 = lane & 15, kg = lane >> 4;
  f32x4 acc[4][4] = {};
  for(int k0=0; k0<K; k0+=64){
    __syncthreads();
    #pragma unroll
    for(int ch=0; ch<4; ch++){
      int off = ch*4096 + tid*16;
      int row = off >> 7;
      int s   = ((off >> 4) & 7) ^ (row & 7);
      __builtin_amdgcn_global_load_lds(
        (const __attribute__((address_space(1))) unsigned int*)(A + (size_t)(bm+row)*K + k0 + s*8),
        (__attribute__((address_space(3))) unsigned int*)((char*)As + off), 16, 0, 0);
    }
    #pragma unroll
    for(int ch=0; ch<4; ch++){
      int off = ch*4096 + tid*16;
      int row = off >> 7;
      int s   = ((off >> 4) & 7) ^ (row & 7);
      __builtin_amdgcn_global_load_lds(
        (const __attribute__((address_space(1))) unsigned int*)(Bt + (size_t)(bn+row)*K + k0 + s*8),
        (__attribute__((address_space(3))) unsigned int*)((char*)Bs + off), 16, 0, 0);
    }
    __syncthreads();
    #pragma unroll
    for(int q=0;q<2;q++){
      s16x8 af[4], bf[4];
      #pragma unroll
      for(int mt=0;mt<4;mt++){
        int row = wm + mt*16 + l15;
        int s = (q*4 + kg) ^ (row & 7);
        af[mt] = *(const s16x8*)(As + row*64 + s*8);
      }
      #pragma unroll
      for(int nt=0;nt<4;nt++){
        int row = wn + nt*16 + l15;
        int s = (q*4 + kg) ^ (row & 7);
        bf[nt] = *(const s16x8*)(Bs + row*64 + s*8);
      }
      #pragma unroll
      for(int mt=0;mt<4;mt++)
        #pragma unroll
        for(int nt=0;nt<4;nt++)
          acc[mt][nt] = __builtin_amdgcn_mfma_f32_16x16x32_bf16(af[mt], bf[nt], acc[mt][nt], 0, 0, 0);
    }
  }
  #pragma unroll
  for(int mt=0;mt<4;mt++){
    #pragma unroll
    for(int nt=0;nt<4;nt++){
      int col = bn + wn + nt*16 + l15;
      float bv = bias ? bias[col] : 0.f;
      #pragma unroll
      for(int e=0;e<4;e++){
        int row = bm + wm + mt*16 + kg*4 + e;
        int orow = remap ? ((row & 15)*T_ + (row >> 4)) : row;
        C[(size_t)orow*N + col] = acc[mt][nt][e] + bv;
      }
    }
  }
}

// ------------- standalone MFMA GEMM kernel (bm0 = row-tile offset) ---------
template<int BF32>
__global__ __launch_bounds__(256)
void k_mm(const unsigned short* __restrict__ A, const void* __restrict__ Bsrc,
          const float* __restrict__ bias, float* __restrict__ C,
          int M, int N, int K, int remap, int bm0){
  __shared__ __align__(16) unsigned short As[128*64];
  __shared__ __align__(16) unsigned short Bs[128*64];
  if(!BF32){
    mm_tile(A, (const unsigned short*)Bsrc, bias, C, N, K,
            bm0 + blockIdx.y*128, blockIdx.x*128, As, Bs, remap);
    return;
  }
  const int tid = threadIdx.x;
  const int lane = tid & 63, w = tid >> 6;
  const int wm = (w>>1)*64, wn = (w&1)*64;
  const int bm = bm0 + blockIdx.y*128, bn = blockIdx.x*128;
  const int l15 = lane & 15, kg = lane >> 4;
  f32x4 acc[4][4] = {};
  for(int k0=0; k0<K; k0+=64){
    __syncthreads();
    #pragma unroll
    for(int ch=0; ch<4; ch++){
      int off = ch*4096 + tid*16;
      int row = off >> 7;
      int s   = ((off >> 4) & 7) ^ (row & 7);
      __builtin_amdgcn_global_load_lds(
        (const __attribute__((address_space(1))) unsigned int*)(A + (size_t)(bm+row)*K + k0 + s*8),
        (__attribute__((address_space(3))) unsigned int*)((char*)As + off), 16, 0, 0);
    }
    {
      const float* Bf = (const float*)Bsrc;
      #pragma unroll
      for(int i=0;i<8;i++){
        int kl = (tid>>5) + i*8;
        int nl = (tid&31)*4;
        float4 v = *(const float4*)(Bf + (size_t)(k0+kl)*N + bn + nl);
        int slot = kl >> 3, kb = kl & 7;
        float vv[4] = {v.x, v.y, v.z, v.w};
        #pragma unroll
        for(int jj=0;jj<4;jj++){
          int n = nl + jj;
          Bs[n*64 + ((slot ^ (n&7))*8) + kb] = f2bf(vv[jj]);
        }
      }
    }
    __syncthreads();
    #pragma unroll
    for(int q=0;q<2;q++){
      s16x8 af[4], bf[4];
      #pragma unroll
      for(int mt=0;mt<4;mt++){
        int row = wm + mt*16 + l15;
        int s = (q*4 + kg) ^ (row & 7);
        af[mt] = *(const s16x8*)(As + row*64 + s*8);
      }
      #pragma unroll
      for(int nt=0;nt<4;nt++){
        int row = wn + nt*16 + l15;
        int s = (q*4 + kg) ^ (row & 7);
        bf[nt] = *(const s16x8*)(Bs + row*64 + s*8);
      }
      #pragma unroll
      for(int mt=0;mt<4;mt++)
        #pragma unroll
        for(int nt=0;nt<4;nt++)
          acc[mt][nt] = __builtin_amdgcn_mfma_f32_16x16x32_bf16(af[mt], bf[nt], acc[mt][nt], 0, 0, 0);
    }
  }
  #pragma unroll
  for(int mt=0;mt<4;mt++){
    #pragma unroll
    for(int nt=0;nt<4;nt++){
      int col = bn + wn + nt*16 + l15;
      float bv = bias ? bias[col] : 0.f;
      #pragma unroll
      for(int e=0;e<4;e++){
        int row = bm + wm + mt*16 + kg*4 + e;
        int orow = remap ? ((row & 15)*T_ + (row >> 4)) : row;
        C[(size_t)orow*N + col] = acc[mt][nt][e] + bv;
      }
    }
  }
}

// ------------- persistent 2-layer LSTM body; TB=1 -> t-major hseq ----------
template<int C, int K, int LAYER, int HU, int TB>
__device__ __forceinline__ void rnn_body(
    unsigned short* __restrict__ Uld, float* __restrict__ zp,
    const unsigned short* __restrict__ Uslice,
    const float* __restrict__ xw0, const float* __restrict__ bpk,
    const unsigned short* __restrict__ h0init, const unsigned short* __restrict__ h1init,
    const float* __restrict__ cinit,
    unsigned short* __restrict__ h0seq, unsigned short* __restrict__ h1seq,
    float* __restrict__ cfin, unsigned* bar, int cb, int nblk, bool det, int myblk)
{
  constexpr int KW = K/4, KS = KW/32, FR = C/16, UB = C/4;
  constexpr int K2 = K*2;
  constexpr int ITEMS = 16*UB;
  const int tid = threadIdx.x;
  const int lane = tid & 63, w = tid >> 6;
  const int l15 = lane & 15, kg = lane >> 4;

  constexpr int CP = (C*K2)/4096;
  #pragma unroll
  for(int i=0;i<CP;i++){
    __builtin_amdgcn_global_load_lds(
      (const __attribute__((address_space(1))) unsigned int*)((const char*)Uslice + i*4096 + tid*16),
      (__attribute__((address_space(3))) unsigned int*)((char*)Uld + i*4096 + tid*16), 16, 0, 0);
  }
  const int base_p = cb*C;
  const int base_u = cb*UB;
  float4 bvr = make_float4(0.f,0.f,0.f,0.f);
  int er = 0, eu = 0;
  if(tid < ITEMS){ er = tid / UB; eu = tid - er*UB; bvr = *(const float4*)(bpk + base_p + eu*4); }
  float creg = 0.f;
  unsigned short* hseqW = LAYER ? h1seq : h0seq;

  int cbyte[FR], cx[FR];
  #pragma unroll
  for(int f=0;f<FR;f++){ int c = f*16 + l15; cbyte[f] = c*K2; cx[f] = (c&7)<<4; }

  __syncthreads();

  for(int it = 0; it <= T_; ++it){
    const bool active = LAYER ? (it >= 1) : (it < T_);
    const int t = LAYER ? it-1 : it;
    if(active){
      const unsigned short* asrc;
      if constexpr(LAYER == 0){
        asrc = (t == 0) ? (h0init + l15*HU)
             : (h0seq + ((size_t)(TB ? ((t-1)*B_ + l15) : (l15*T_ + (t-1))))*HU);
      } else {
        if(w < 2){
          asrc = h0seq + ((size_t)(TB ? (t*B_ + l15) : (l15*T_ + t)))*HU;
        } else {
          asrc = ((t == 0) ? (h1init + l15*HU)
               : (h1seq + ((size_t)(TB ? ((t-1)*B_ + l15) : (l15*T_ + (t-1))))*HU)) - HU;
        }
      }
      f32x4 acc[FR];
      #pragma unroll
      for(int f=0;f<FR;f++) acc[f] = (f32x4){0.f,0.f,0.f,0.f};
      #pragma unroll
      for(int s=0;s<KS;s++){
        const int kel = w*KW + s*32 + kg*8;
        s16x8 a = *(const s16x8*)(asrc + kel);
        const int kb  = kel*2;
        const int kch = kb & ~127;
        const int ksl = (kb >> 4) & 7;
        #pragma unroll
        for(int f=0;f<FR;f++){
          const int ad = cbyte[f] + kch + ((ksl<<4) ^ cx[f]);
          s16x8 b = *(const s16x8*)((const char*)Uld + ad);
          acc[f] = __builtin_amdgcn_mfma_f32_16x16x32_bf16(a, b, acc[f], 0, 0, 0);
        }
      }
      #pragma unroll
      for(int f=0;f<FR;f++)
        #pragma unroll
        for(int e=0;e<4;e++)
          zp[(w*16 + kg*4 + e)*68 + f*16 + l15] = acc[f][e];
    }
    __syncthreads();
    if(active && tid < ITEMS){
      float4 z0 = *(const float4*)(zp + (     er)*68 + eu*4);
      float4 z1 = *(const float4*)(zp + (16 + er)*68 + eu*4);
      float4 z2 = *(const float4*)(zp + (32 + er)*68 + eu*4);
      float4 z3 = *(const float4*)(zp + (48 + er)*68 + eu*4);
      float si = z0.x+z1.x+z2.x+z3.x + bvr.x;
      float sf = z0.y+z1.y+z2.y+z3.y + bvr.y;
      float sg = z0.z+z1.z+z2.z+z3.z + bvr.z;
      float so = z0.w+z1.w+z2.w+z3.w + bvr.w;
      if constexpr(LAYER == 0){
        float4 xv = *(const float4*)(xw0 + ((size_t)(er*T_ + t))*(4*HU) + base_p + eu*4);
        si += xv.x; sf += xv.y; sg += xv.z; so += xv.w;
      }
      float cin = (t == 0) ? cinit[er*HU + base_u + eu] : creg;
      float c2 = sigm(sf)*cin + sigm(si)*tanhf(sg);
      float h2 = sigm(so)*tanhf(c2);
      creg = c2;
      size_t hrow = TB ? ((size_t)(t*B_ + er)) : ((size_t)(er*T_ + t));
      store_coh16(&hseqW[hrow*HU + base_u + eu], (unsigned)f2bf(h2));
      if(t == T_-1) store_cohf(&cfin[er*HU + base_u + eu], c2);
    }
    if(it < T_) gbar3(bar, (unsigned)(it+1), nblk, det, myblk);
  }
  // final publish: flag value T_+1 = 65
  asm volatile("s_waitcnt vmcnt(0)" ::: "memory");
  __syncthreads();
  if(tid == 0) store_cohu(bar + (size_t)myblk*16, (unsigned)(T_+1));
}

// ------------- mega kernel 1: RNN1 (blocks 0..63) + spare prep + proj1 -----
__global__ __launch_bounds__(256, 1)
void k_rnn1m(const unsigned short* __restrict__ Ut0, const unsigned short* __restrict__ WU1,
    const float* __restrict__ xw0, const float* __restrict__ bpk0, const float* __restrict__ bpk1,
    const unsigned short* __restrict__ h0init, const unsigned short* __restrict__ h1init,
    const float* __restrict__ c0init, const float* __restrict__ c1init,
    unsigned short* __restrict__ h0seq, unsigned short* __restrict__ h1seq,
    float* __restrict__ c0fin, float* __restrict__ c1fin, unsigned* bar,
    const int* __restrict__ ids2, const float* __restrict__ emb, unsigned short* __restrict__ ebuf2,
    const float* __restrict__ b2_0, const float* __restrict__ b2_1,
    float* __restrict__ bpk20, float* __restrict__ bpk21,
    const float* __restrict__ U2_0, unsigned short* __restrict__ ut0_2,
    const float* __restrict__ W2_0, unsigned short* __restrict__ wtmp2,
    const float* __restrict__ W2_1, const float* __restrict__ U2_1, unsigned short* __restrict__ wu1_2,
    const float* __restrict__ Wp1, unsigned short* __restrict__ wpT1,
    const float* __restrict__ bp1, float* __restrict__ out1, int wide)
{
  constexpr int HU = 512, C0 = 64, C1 = 64;
  constexpr int NB0 = 4*HU/C0;         // 32
  constexpr int NRNN = NB0 + 4*HU/C1;  // 64
  constexpr int NS = 256 - NRNN;       // 192 spare
  __shared__ __align__(16) unsigned short Uld[65536];
  __shared__ __align__(16) float zred[64*68];
  const int blk = blockIdx.x;
  const int tid = threadIdx.x;
  if(blk < NB0){
    rnn_body<C0, HU, 0, HU, 1>(Uld, zred, Ut0 + (size_t)blk*C0*HU, xw0, bpk0,
        h0init, h1init, c0init, h0seq, h1seq, c0fin, bar, blk, NRNN, blk==0, blk);
  } else if(blk < NRNN){
    rnn_body<C1, 2*HU, 1, HU, 1>(Uld, zred, WU1 + (size_t)(blk-NB0)*C1*2*HU, nullptr, bpk1,
        h0init, h1init, c1init, h0seq, h1seq, c1fin, bar, blk-NB0, NRNN, false, blk);
  } else {
    const int q = blk - NRNN;          // 0..191
    float (*tile)[33] = (float(*)[33])Uld;
    unsigned short* As = Uld;
    unsigned short* Bs = Uld + 8192;
    volatile int* rdy = (volatile int*)((char*)Uld + 128000);
    // ---- phase 1: prep jobs (RNN2 weights/inputs + wpT1 cvt) ----
    const int J0 = 512, J1 = J0+32, J2 = J1+4096, J3 = J2+2048, J4 = J3+4096, J5 = J4+4096;
    const int totJ = wide ? (J5 + 16000) : J5;
    for(int j = q; j < totJ; j += NS){
      if(j < J0){
        int row = j*2 + (tid>>7);
        int id = ids2[row];
        float4 v = *(const float4*)(emb + (size_t)id*E_ + (tid&127)*4);
        ushort4 o; o.x=f2bf(v.x); o.y=f2bf(v.y); o.z=f2bf(v.z); o.w=f2bf(v.w);
        *(ushort4*)(ebuf2 + (size_t)row*E_ + (tid&127)*4) = o;
      } else if(j < J1){
        int jj = j - J0;
        const float* b = (jj < 16) ? b2_0 : b2_1;
        float* o = (jj < 16) ? bpk20 : bpk21;
        int p = (jj & 15)*256 + tid;
        o[p] = b[(p&3)*1024 + (p>>2)];
      } else if(j < J2){
        int r = j - J1; tcvt_dev(U2_0, ut0_2, 4096, 1024, 1024, 0, 1, r%128, r/128, tile);
      } else if(j < J3){
        int r = j - J2; tcvt_dev(W2_0, wtmp2, 4096, 1024, 512, 0, 0, r%128, r/128, tile);
      } else if(j < J4){
        int r = j - J3; tcvt_dev(W2_1, wu1_2, 4096, 1024, 2048, 0, 1, r%128, r/128, tile);
      } else if(j < J5){
        int r = j - J4; tcvt_dev(U2_1, wu1_2, 4096, 1024, 2048, 1024, 1, r%128, r/128, tile);
      } else {
        int r = j - J5; tcvt_dev(Wp1, wpT1, 32000, 0, 512, 0, 0, r%1000, r/1000, tile);
      }
    }
    if(!wide) return;
    // ---- phase 2: make wpT1 visible cross-XCD, then spare barrier ----
    __syncthreads();
    __threadfence();
    if(tid == 0)
      __hip_atomic_fetch_add(bar + 5120, 1u, __ATOMIC_RELAXED, __HIP_MEMORY_SCOPE_AGENT);
    if(tid == 0){
      while(load_coh(bar + 5120) < (unsigned)NS) __builtin_amdgcn_s_sleep(8);
    }
    __syncthreads();
    // ---- phase 3: proj1 pipelined against RNN1 L1 progress ----
    for(int g = 0; g < 8; ++g){
      const unsigned req = 8u*(unsigned)g + 9u;
      for(;;){
        if(tid == 0) *rdy = 1;
        __syncthreads();
        if(tid < 32){
          if(load_coh(bar + (size_t)(NB0 + tid)*16) < req) *rdy = 0;
        }
        __syncthreads();
        if(*rdy) break;
        __builtin_amdgcn_s_sleep(16);
      }
      for(int n = q; n < 250; n += NS)
        mm_tile(h1seq, wpT1, bp1, out1, V_, 512, g*128, n*128, As, Bs, 1);
    }
  }
}

// ------------- mega kernel 2: RNN2 (blocks 0..191) + wpT2 cvt + proj2 ------
__global__ __launch_bounds__(256, 1)
void k_rnn2m(const unsigned short* __restrict__ Ut0, const unsigned short* __restrict__ WU1,
    const float* __restrict__ xw0, const float* __restrict__ bpk0, const float* __restrict__ bpk1,
    const unsigned short* __restrict__ h0init, const unsigned short* __restrict__ h1init,
    const float* __restrict__ c0init, const float* __restrict__ c1init,
    unsigned short* __restrict__ h0seq, unsigned short* __restrict__ h1seq,
    float* __restrict__ c0fin, float* __restrict__ c1fin, unsigned* bar,
    const float* __restrict__ Wp2, unsigned short* __restrict__ wpT2,
    const float* __restrict__ bp2, float* __restrict__ out2, int wide)
{
  constexpr int HU = 1024, C0 = 64, C1 = 32;
  constexpr int NB0 = 4*HU/C0;          // 64
  constexpr int NRNN = NB0 + 4*HU/C1;   // 192
  constexpr int NS = 64;                // spares
  __shared__ __align__(16) unsigned short Uld[65536];
  __shared__ __align__(16) float zred[64*68];
  const int blk = blockIdx.x;
  const int tid = threadIdx.x;
  if(blk < NB0){
    rnn_body<C0, HU, 0, HU, 1>(Uld, zred, Ut0 + (size_t)blk*C0*HU, xw0, bpk0,
        h0init, h1init, c0init, h0seq, h1seq, c0fin, bar, blk, NRNN, blk==0, blk);
  } else if(blk < NRNN){
    rnn_body<C1, 2*HU, 1, HU, 1>(Uld, zred, WU1 + (size_t)(blk-NB0)*C1*2*HU, nullptr, bpk1,
        h0init, h1init, c1init, h0seq, h1seq, c1fin, bar, blk-NB0, NRNN, false, blk);
  } else if(wide){
    const int q = blk - NRNN;            // 0..63
    float (*tile)[33] = (float(*)[33])Uld;
    unsigned short* As = Uld;
    unsigned short* Bs = Uld + 8192;
    volatile int* rdy = (volatile int*)((char*)Uld + 128000);
    // ---- phase A: wpT2 = Wp2^T bf16 ----
    for(int j = q; j < 32000; j += NS)
      tcvt_dev(Wp2, wpT2, 32000, 0, 1024, 0, 0, j%1000, j/1000, tile);
    __syncthreads();
    __threadfence();
    if(tid == 0)
      __hip_atomic_fetch_add(bar + 5120, 1u, __ATOMIC_RELAXED, __HIP_MEMORY_SCOPE_AGENT);
    if(tid == 0){
      while(load_coh(bar + 5120) < (unsigned)NS) __builtin_amdgcn_s_sleep(8);
    }
    __syncthreads();
    // ---- phase B: proj2 groups g=0,1 gated on the 128 L1 flags ----
    for(int g = 0; g < 2; ++g){
      const unsigned req = 8u*(unsigned)g + 9u;
      for(;;){
        if(tid == 0) *rdy = 1;
        __syncthreads();
        if(tid < 128){
          if(load_coh(bar + (size_t)(NB0 + tid)*16) < req) *rdy = 0;
        }
        __syncthreads();
        if(*rdy) break;
        __builtin_amdgcn_s_sleep(16);
      }
      for(int n = q; n < 250; n += NS)
        mm_tile(h1seq, wpT2, bp2, out2, V_, 1024, g*128, n*128, As, Bs, 1);
    }
  }
}

// ---------------------------------------------------------------------------
extern "C" void kernel_launch(void* const* d_in, const int* in_sizes, int n_in,
                              void* d_out, int out_size, void* d_ws, size_t ws_size,
                              hipStream_t stream){
  const int*   ids1 = (const int*)d_in[0];
  const int*   ids2 = (const int*)d_in[1];
  const float* init = (const float*)d_in[2];
  const float* emb  = (const float*)d_in[3];
  const float* W1_0 = (const float*)d_in[4];
  const float* U1_0 = (const float*)d_in[5];
  const float* b1_0 = (const float*)d_in[6];
  const float* W1_1 = (const float*)d_in[7];
  const float* U1_1 = (const float*)d_in[8];
  const float* b1_1 = (const float*)d_in[9];
  const float* W2_0 = (const float*)d_in[10];
  const float* U2_0 = (const float*)d_in[11];
  const float* b2_0 = (const float*)d_in[12];
  const float* W2_1 = (const float*)d_in[13];
  const float* U2_1 = (const float*)d_in[14];
  const float* b2_1 = (const float*)d_in[15];
  const float* Wp1  = (const float*)d_in[16];
  const float* bp1  = (const float*)d_in[17];
  const float* Wp2  = (const float*)d_in[18];
  const float* bp2  = (const float*)d_in[19];
  float* out1 = (float*)d_out;
  float* out2 = out1 + (size_t)B_*T_*V_;

  char* base = (char*)d_ws;
  float*          xw    = (float*)(base);                           // 16 MB
  unsigned short* ut0_1 = (unsigned short*)(base + (16u<<20));      // 2 MB
  unsigned short* wu1_1 = (unsigned short*)(base + (18u<<20));      // 4 MB
  unsigned short* ut0_2 = (unsigned short*)(base + (22u<<20));      // 8 MB
  unsigned short* wu1_2 = (unsigned short*)(base + (30u<<20));      // 16 MB
  unsigned short* wtmp  = (unsigned short*)(base + (46u<<20));      // 4 MB
  unsigned short* ebuf  = (unsigned short*)(base + (50u<<20));      // 1 MB
  unsigned short* h0s1  = (unsigned short*)(base + (51u<<20));      // 1 MB  [t*B+b]
  unsigned short* h1s1  = (unsigned short*)(base + (52u<<20));      // 1 MB  [t*B+b]
  unsigned short* h0s2  = (unsigned short*)(base + (53u<<20));      // 2 MB  [t*B+b]
  unsigned short* h1s2  = (unsigned short*)(base + (55u<<20));      // 2 MB  [t*B+b]
  char* M = base + (57u<<20);
  unsigned short* h0i1 = (unsigned short*)(M);
  unsigned short* h1i1 = (unsigned short*)(M + 16384);
  float* c0i1 = (float*)(M + 32768);
  float* c1i1 = (float*)(M + 65536);
  unsigned short* h2i0 = (unsigned short*)(M + 98304);
  unsigned short* h2i1 = (unsigned short*)(M + 131072);
  float* c2i0 = (float*)(M + 163840);
  float* c2i1 = (float*)(M + 229376);
  float* c0f1 = (float*)(M + 294912);
  float* c1f1 = (float*)(M + 327680);
  float* c0f2 = (float*)(M + 360448);
  float* c1f2 = (float*)(M + 425984);
  float* bpk10 = (float*)(M + 491520);
  float* bpk11 = (float*)(M + 499712);
  float* bpk20 = (float*)(M + 507904);
  float* bpk21 = (float*)(M + 524288);
  unsigned* bar1 = (unsigned*)(M + 540672);            // 32 KB
  unsigned* bar2 = (unsigned*)(M + 540672 + 32768);    // 32 KB
  unsigned short* wpT1 = (unsigned short*)(base + (58u<<20));  // 31.25 MiB
  unsigned short* wpT2 = (unsigned short*)(base + (90u<<20));  // 62.5 MiB
  const size_t NEED_ALL = ((size_t)90u<<20) + (size_t)V_*1024*2;
  const bool wide = ws_size >= NEED_ALL;

  k_barinit<<<dim3(64), dim3(256), 0, stream>>>(bar1);

  // ===== RNN1 prep =====
  k_init1<<<dim3(32), dim3(256), 0, stream>>>(init, h0i1, c0i1, h1i1, c1i1);
  k_gather<<<dim3(B_*T_), dim3(128), 0, stream>>>(ids1, emb, ebuf);
  k_tcvt<<<dim3(64, 16), dim3(256), 0, stream>>>(U1_0, ut0_1, 2048, 512, 512, 0, 1);
  k_tcvt<<<dim3(64, 16), dim3(256), 0, stream>>>(W1_0, wtmp,  2048, 512, 512, 0, 0);
  k_tcvt<<<dim3(64, 16), dim3(256), 0, stream>>>(W1_1, wu1_1, 2048, 512, 1024, 0, 1);
  k_tcvt<<<dim3(64, 16), dim3(256), 0, stream>>>(U1_1, wu1_1, 2048, 512, 1024, 512, 1);
  k_bpack<<<dim3(8),  dim3(256), 0, stream>>>(b1_0, bpk10, 512, 2048);
  k_bpack<<<dim3(8),  dim3(256), 0, stream>>>(b1_1, bpk11, 512, 2048);
  k_mm<0><<<dim3(16, 8), dim3(256), 0, stream>>>(ebuf, wtmp, nullptr, xw, 1024, 2048, 512, 0, 0);

  // ===== RNN1 + hidden: RNN2 prep, wpT1 cvt, pipelined proj1 =====
  k_rnn1m<<<dim3(256), dim3(256), 0, stream>>>(ut0_1, wu1_1, xw, bpk10, bpk11,
      h0i1, h1i1, c0i1, c1i1, h0s1, h1s1, c0f1, c1f1, bar1,
      ids2, emb, ebuf, b2_0, b2_1, bpk20, bpk21,
      U2_0, ut0_2, W2_0, wtmp, W2_1, U2_1, wu1_2, Wp1, wpT1, bp1, out1, (int)wide);

  if(!wide){
    k_mm<1><<<dim3(250, 8), dim3(256), 0, stream>>>(h1s1, Wp1, bp1, out1, 1024, V_, 512, 1, 0);
  }

  // xw2 = e2 @ W2_0
  k_mm<0><<<dim3(32, 8), dim3(256), 0, stream>>>(ebuf, wtmp, nullptr, xw, 1024, 4096, 512, 0, 0);
  k_init2<<<dim3(64, 2), dim3(256), 0, stream>>>(init, h0s1, h1s1, c0f1, c1f1,
                                                 h2i0, h2i1, c2i0, c2i1);

  // ===== RNN2 + hidden: wpT2 cvt + proj2 rows 0..255 =====
  k_rnn2m<<<dim3(256), dim3(256), 0, stream>>>(ut0_2, wu1_2, xw, bpk20, bpk21,
      h2i0, h2i1, c2i0, c2i1, h0s2, h1s2, c0f2, c1f2, bar2,
      Wp2, wpT2, bp2, out2, (int)wide);

  // ===== projection 2 remainder =====
  if(wide){
    k_mm<0><<<dim3(250, 6), dim3(256), 0, stream>>>(h1s2, wpT2, bp2, out2, 1024, V_, 1024, 1, 256);
  } else {
    k_mm<1><<<dim3(250, 8), dim3(256), 0, stream>>>(h1s2, Wp2, bp2, out2, 1024, V_, 1024, 1, 0);
  }
}

// Round 13
// 1029.003 us; speedup vs baseline: 1.0050x; 1.0050x over previous
//
#include <hip/hip_runtime.h>
#include <hip/hip_bf16.h>

#define B_ 16
#define T_ 64
#define E_ 512
#define H_ 512
#define V_ 32000

typedef __attribute__((ext_vector_type(4))) float f32x4;
typedef __attribute__((ext_vector_type(8))) short s16x8;

__device__ __forceinline__ float sigm(float x){ return 1.0f/(1.0f + __expf(-x)); }

__device__ __forceinline__ unsigned short f2bf(float x){
  unsigned int u = __float_as_uint(x);
  return (unsigned short)((u + 0x7FFFu + ((u>>16)&1u)) >> 16);
}

// ---- coherence-point ops (no cache-wide writeback/invalidate anywhere) ----
__device__ __forceinline__ unsigned load_coh(const unsigned* p){
  unsigned v;
  asm volatile("global_load_dword %0, %1, off sc0 sc1\n\ts_waitcnt vmcnt(0)"
               : "=v"(v) : "v"(p) : "memory");
  return v;
}
__device__ __forceinline__ void store_coh16(unsigned short* p, unsigned v){
  asm volatile("global_store_short %0, %1, off sc0 sc1" :: "v"(p), "v"(v) : "memory");
}
__device__ __forceinline__ void store_cohf(float* p, float v){
  asm volatile("global_store_dword %0, %1, off sc0 sc1" :: "v"(p), "v"(v) : "memory");
}
__device__ __forceinline__ void store_cohu(unsigned* p, unsigned v){
  asm volatile("global_store_dword %0, %1, off sc0 sc1" :: "v"(p), "v"(v) : "memory");
}

// ---- grid barrier: RMW-free flags + detector; gen sharded on 8 lines ------
__device__ __forceinline__ void gbar3(unsigned* barb, unsigned bi1, int nblk,
                                      bool det, int myblk){
  asm volatile("s_waitcnt vmcnt(0)" ::: "memory");
  __syncthreads();
  const int tid = threadIdx.x;
  if(tid == 0) store_cohu(barb + (size_t)myblk*16, bi1);
  if(det){
    if(tid < nblk){
      const unsigned* fp = barb + (size_t)tid*16;
      while(load_coh(fp) < bi1) __builtin_amdgcn_s_sleep(1);
    }
    __syncthreads();
    if(tid < 8) store_cohu(barb + 4096 + (size_t)tid*16, bi1);
  } else {
    if(tid == 0){
      const unsigned* gp = barb + 4096 + (size_t)(myblk & 7)*16;
      while(load_coh(gp) < bi1) __builtin_amdgcn_s_sleep(1);
    }
  }
  __syncthreads();
}

__global__ void k_barinit(unsigned* bar){
  int i = blockIdx.x*256 + threadIdx.x;
  if(i < 16384) bar[i] = 0u;
}

// ------------- embedding gather -> bf16 ------------------------------------
__global__ void k_gather(const int* __restrict__ ids, const float* __restrict__ emb,
                         unsigned short* __restrict__ out){
  const int row = blockIdx.x;
  const int id  = ids[row];
  float4 v = *(const float4*)(emb + (size_t)id*E_ + threadIdx.x*4);
  ushort4 o;
  o.x = f2bf(v.x); o.y = f2bf(v.y); o.z = f2bf(v.z); o.w = f2bf(v.w);
  *(ushort4*)(out + (size_t)row*E_ + threadIdx.x*4) = o;
}

// ------------- transpose+convert(+permute)(+swizzle), 32x32 tile -----------
__device__ __forceinline__ void tcvt_dev(const float* __restrict__ in,
    unsigned short* __restrict__ out, int N, int Hp, int Kfull, int koff, int swz,
    int bx, int by, float (*tile)[33]){
  const int n0 = bx*32, k0 = by*32;
  const int x = threadIdx.x & 31, y = threadIdx.x >> 5;
  __syncthreads();
  #pragma unroll
  for(int i=0;i<4;i++){
    int k = y + i*8;
    tile[k][x] = in[(size_t)(k0+k)*N + n0 + x];
  }
  __syncthreads();
  #pragma unroll
  for(int i=0;i<4;i++){
    int nl = y + i*8;
    int n  = n0 + nl;
    int p  = Hp ? ((n % Hp)*4 + n / Hp) : n;
    int kk = koff + k0 + x;
    size_t idx;
    if(swz){
      int k2 = kk*2;
      int slot = ((k2>>4)&7) ^ (p&7);
      idx = (size_t)p*Kfull + (((k2 & ~127) | (slot<<4) | (k2 & 15)) >> 1);
    } else {
      idx = (size_t)p*Kfull + kk;
    }
    out[idx] = f2bf(tile[x][nl]);
  }
}

__global__ __launch_bounds__(256)
void k_tcvt(const float* __restrict__ in, unsigned short* __restrict__ out,
            int N, int Hp, int Kfull, int koff, int swz){
  __shared__ float tile[32][33];
  tcvt_dev(in, out, N, Hp, Kfull, koff, swz, blockIdx.x, blockIdx.y, tile);
}

// ------------- WIDE transpose-cvt: 32 k-rows x 256 n-cols per call ---------
// f32 [K][N] -> bf16 [N][K], no permute/swizzle. Coalesced reads, 64B/thr writes.
__device__ __forceinline__ void tcvtw_dev(const float* __restrict__ in,
    unsigned short* __restrict__ out, int N, int K, int bx, int by,
    float (*tile)[257]){
  const int tid = threadIdx.x;
  const int n0 = bx*256, k0 = by*32;
  const int row = tid >> 3, nc = (tid & 7)*32;
  __syncthreads();
  #pragma unroll
  for(int j=0;j<8;j++){
    float4 v = *(const float4*)(in + (size_t)(k0+row)*N + n0 + nc + j*4);
    *(float4*)&tile[row][nc + j*4] = v;
  }
  __syncthreads();
  __align__(16) unsigned short vals[32];
  #pragma unroll
  for(int k=0;k<32;k++) vals[k] = f2bf(tile[k][tid]);
  unsigned short* op = out + (size_t)(n0+tid)*K + k0;
  #pragma unroll
  for(int j=0;j<4;j++)
    *(uint4*)(op + j*8) = *(const uint4*)&vals[j*8];
}

// ------------- bias permute -------------------------------------------------
__global__ void k_bpack(const float* __restrict__ b, float* __restrict__ out, int H, int N){
  int p = blockIdx.x*256 + threadIdx.x;
  if(p < N) out[p] = b[(p&3)*H + (p>>2)];
}

// ------------- init states --------------------------------------------------
__global__ void k_init1(const float* __restrict__ init_state,
                        unsigned short* h0i, float* c0i, unsigned short* h1i, float* c1i){
  int i = blockIdx.x*256 + threadIdx.x;
  if(i >= B_*H_) return;
  float v0 = init_state[i];
  float v1 = init_state[B_*H_ + i];
  h0i[i] = f2bf(v0); c0i[i] = v0;
  h1i[i] = f2bf(v1); c1i[i] = v1;
}

// h0seq1/h1seq1 are T-MAJOR ([t*B+b]) — final row at t=63.
__global__ void k_init2(const float* __restrict__ init_state,
                        const unsigned short* __restrict__ h0seq1,
                        const unsigned short* __restrict__ h1seq1,
                        const float* __restrict__ c0f1, const float* __restrict__ c1f1,
                        unsigned short* h20i, unsigned short* h21i,
                        float* c20i, float* c21i){
  const int l = blockIdx.y;
  int i = blockIdx.x*256 + threadIdx.x;
  if(i >= B_*2*H_) return;
  const int r = i >> 10, j = i & 1023;
  unsigned short* ho = l ? h21i : h20i;
  float* co = l ? c21i : c20i;
  if(j < H_){
    float v = init_state[(size_t)l*B_*H_ + r*H_ + j];
    ho[i] = f2bf(v); co[i] = v;
  } else {
    const unsigned short* hs = l ? h1seq1 : h0seq1;
    const float* cf = l ? c1f1 : c0f1;
    ho[i] = hs[(size_t)((T_-1)*B_ + r)*H_ + (j - H_)];
    co[i] = cf[r*H_ + (j - H_)];
  }
}

// ------------- MFMA GEMM tile (B pre-transposed bf16); optional row remap --
__device__ __forceinline__ void mm_tile(const unsigned short* __restrict__ A,
    const unsigned short* __restrict__ Bt, const float* __restrict__ bias,
    float* __restrict__ C, int N, int K, int bm, int bn,
    unsigned short* As, unsigned short* Bs, int remap){
  const int tid = threadIdx.x;
  const int lane = tid & 63, w = tid >> 6;
  const int wm = (w>>1)*64, wn = (w&1)*64;
  const int l15 = lane & 15, kg = lane >> 4;
  f32x4 acc[4][4] = {};
  for(int k0=0; k0<K; k0+=64){
    __syncthreads();
    #pragma unroll
    for(int ch=0; ch<4; ch++){
      int off = ch*4096 + tid*16;
      int row = off >> 7;
      int s   = ((off >> 4) & 7) ^ (row & 7);
      __builtin_amdgcn_global_load_lds(
        (const __attribute__((address_space(1))) unsigned int*)(A + (size_t)(bm+row)*K + k0 + s*8),
        (__attribute__((address_space(3))) unsigned int*)((char*)As + off), 16, 0, 0);
    }
    #pragma unroll
    for(int ch=0; ch<4; ch++){
      int off = ch*4096 + tid*16;
      int row = off >> 7;
      int s   = ((off >> 4) & 7) ^ (row & 7);
      __builtin_amdgcn_global_load_lds(
        (const __attribute__((address_space(1))) unsigned int*)(Bt + (size_t)(bn+row)*K + k0 + s*8),
        (__attribute__((address_space(3))) unsigned int*)((char*)Bs + off), 16, 0, 0);
    }
    __syncthreads();
    #pragma unroll
    for(int q=0;q<2;q++){
      s16x8 af[4], bf[4];
      #pragma unroll
      for(int mt=0;mt<4;mt++){
        int row = wm + mt*16 + l15;
        int s = (q*4 + kg) ^ (row & 7);
        af[mt] = *(const s16x8*)(As + row*64 + s*8);
      }
      #pragma unroll
      for(int nt=0;nt<4;nt++){
        int row = wn + nt*16 + l15;
        int s = (q*4 + kg) ^ (row & 7);
        bf[nt] = *(const s16x8*)(Bs + row*64 + s*8);
      }
      #pragma unroll
      for(int mt=0;mt<4;mt++)
        #pragma unroll
        for(int nt=0;nt<4;nt++)
          acc[mt][nt] = __builtin_amdgcn_mfma_f32_16x16x32_bf16(af[mt], bf[nt], acc[mt][nt], 0, 0, 0);
    }
  }
  #pragma unroll
  for(int mt=0;mt<4;mt++){
    #pragma unroll
    for(int nt=0;nt<4;nt++){
      int col = bn + wn + nt*16 + l15;
      float bv = bias ? bias[col] : 0.f;
      #pragma unroll
      for(int e=0;e<4;e++){
        int row = bm + wm + mt*16 + kg*4 + e;
        int orow = remap ? ((row & 15)*T_ + (row >> 4)) : row;
        C[(size_t)orow*N + col] = acc[mt][nt][e] + bv;
      }
    }
  }
}

// ------------- standalone MFMA GEMM kernel (bm0 = row offset) --------------
template<int BF32>
__global__ __launch_bounds__(256)
void k_mm(const unsigned short* __restrict__ A, const void* __restrict__ Bsrc,
          const float* __restrict__ bias, float* __restrict__ C,
          int M, int N, int K, int remap, int bm0){
  __shared__ __align__(16) unsigned short As[128*64];
  __shared__ __align__(16) unsigned short Bs[128*64];
  if(!BF32){
    mm_tile(A, (const unsigned short*)Bsrc, bias, C, N, K,
            bm0 + blockIdx.y*128, blockIdx.x*128, As, Bs, remap);
    return;
  }
  const int tid = threadIdx.x;
  const int lane = tid & 63, w = tid >> 6;
  const int wm = (w>>1)*64, wn = (w&1)*64;
  const int bm = bm0 + blockIdx.y*128, bn = blockIdx.x*128;
  const int l15 = lane & 15, kg = lane >> 4;
  f32x4 acc[4][4] = {};
  for(int k0=0; k0<K; k0+=64){
    __syncthreads();
    #pragma unroll
    for(int ch=0; ch<4; ch++){
      int off = ch*4096 + tid*16;
      int row = off >> 7;
      int s   = ((off >> 4) & 7) ^ (row & 7);
      __builtin_amdgcn_global_load_lds(
        (const __attribute__((address_space(1))) unsigned int*)(A + (size_t)(bm+row)*K + k0 + s*8),
        (__attribute__((address_space(3))) unsigned int*)((char*)As + off), 16, 0, 0);
    }
    {
      const float* Bf = (const float*)Bsrc;
      #pragma unroll
      for(int i=0;i<8;i++){
        int kl = (tid>>5) + i*8;
        int nl = (tid&31)*4;
        float4 v = *(const float4*)(Bf + (size_t)(k0+kl)*N + bn + nl);
        int slot = kl >> 3, kb = kl & 7;
        float vv[4] = {v.x, v.y, v.z, v.w};
        #pragma unroll
        for(int jj=0;jj<4;jj++){
          int n = nl + jj;
          Bs[n*64 + ((slot ^ (n&7))*8) + kb] = f2bf(vv[jj]);
        }
      }
    }
    __syncthreads();
    #pragma unroll
    for(int q=0;q<2;q++){
      s16x8 af[4], bf[4];
      #pragma unroll
      for(int mt=0;mt<4;mt++){
        int row = wm + mt*16 + l15;
        int s = (q*4 + kg) ^ (row & 7);
        af[mt] = *(const s16x8*)(As + row*64 + s*8);
      }
      #pragma unroll
      for(int nt=0;nt<4;nt++){
        int row = wn + nt*16 + l15;
        int s = (q*4 + kg) ^ (row & 7);
        bf[nt] = *(const s16x8*)(Bs + row*64 + s*8);
      }
      #pragma unroll
      for(int mt=0;mt<4;mt++)
        #pragma unroll
        for(int nt=0;nt<4;nt++)
          acc[mt][nt] = __builtin_amdgcn_mfma_f32_16x16x32_bf16(af[mt], bf[nt], acc[mt][nt], 0, 0, 0);
    }
  }
  #pragma unroll
  for(int mt=0;mt<4;mt++){
    #pragma unroll
    for(int nt=0;nt<4;nt++){
      int col = bn + wn + nt*16 + l15;
      float bv = bias ? bias[col] : 0.f;
      #pragma unroll
      for(int e=0;e<4;e++){
        int row = bm + wm + mt*16 + kg*4 + e;
        int orow = remap ? ((row & 15)*T_ + (row >> 4)) : row;
        C[(size_t)orow*N + col] = acc[mt][nt][e] + bv;
      }
    }
  }
}

// ------------- persistent 2-layer LSTM body; TB=1 -> t-major hseq ----------
template<int C, int K, int LAYER, int HU, int TB>
__device__ __forceinline__ void rnn_body(
    unsigned short* __restrict__ Uld, float* __restrict__ zp,
    const unsigned short* __restrict__ Uslice,
    const float* __restrict__ xw0, const float* __restrict__ bpk,
    const unsigned short* __restrict__ h0init, const unsigned short* __restrict__ h1init,
    const float* __restrict__ cinit,
    unsigned short* __restrict__ h0seq, unsigned short* __restrict__ h1seq,
    float* __restrict__ cfin, unsigned* bar, int cb, int nblk, bool det, int myblk)
{
  constexpr int KW = K/4, KS = KW/32, FR = C/16, UB = C/4;
  constexpr int K2 = K*2;
  constexpr int ITEMS = 16*UB;
  const int tid = threadIdx.x;
  const int lane = tid & 63, w = tid >> 6;
  const int l15 = lane & 15, kg = lane >> 4;

  constexpr int CP = (C*K2)/4096;
  #pragma unroll
  for(int i=0;i<CP;i++){
    __builtin_amdgcn_global_load_lds(
      (const __attribute__((address_space(1))) unsigned int*)((const char*)Uslice + i*4096 + tid*16),
      (__attribute__((address_space(3))) unsigned int*)((char*)Uld + i*4096 + tid*16), 16, 0, 0);
  }
  const int base_p = cb*C;
  const int base_u = cb*UB;
  float4 bvr = make_float4(0.f,0.f,0.f,0.f);
  int er = 0, eu = 0;
  if(tid < ITEMS){ er = tid / UB; eu = tid - er*UB; bvr = *(const float4*)(bpk + base_p + eu*4); }
  float creg = 0.f;
  unsigned short* hseqW = LAYER ? h1seq : h0seq;

  int cbyte[FR], cx[FR];
  #pragma unroll
  for(int f=0;f<FR;f++){ int c = f*16 + l15; cbyte[f] = c*K2; cx[f] = (c&7)<<4; }

  __syncthreads();

  for(int it = 0; it <= T_; ++it){
    const bool active = LAYER ? (it >= 1) : (it < T_);
    const int t = LAYER ? it-1 : it;
    if(active){
      const unsigned short* asrc;
      if constexpr(LAYER == 0){
        asrc = (t == 0) ? (h0init + l15*HU)
             : (h0seq + ((size_t)(TB ? ((t-1)*B_ + l15) : (l15*T_ + (t-1))))*HU);
      } else {
        if(w < 2){
          asrc = h0seq + ((size_t)(TB ? (t*B_ + l15) : (l15*T_ + t)))*HU;
        } else {
          asrc = ((t == 0) ? (h1init + l15*HU)
               : (h1seq + ((size_t)(TB ? ((t-1)*B_ + l15) : (l15*T_ + (t-1))))*HU)) - HU;
        }
      }
      f32x4 acc[FR];
      #pragma unroll
      for(int f=0;f<FR;f++) acc[f] = (f32x4){0.f,0.f,0.f,0.f};
      #pragma unroll
      for(int s=0;s<KS;s++){
        const int kel = w*KW + s*32 + kg*8;
        s16x8 a = *(const s16x8*)(asrc + kel);
        const int kb  = kel*2;
        const int kch = kb & ~127;
        const int ksl = (kb >> 4) & 7;
        #pragma unroll
        for(int f=0;f<FR;f++){
          const int ad = cbyte[f] + kch + ((ksl<<4) ^ cx[f]);
          s16x8 b = *(const s16x8*)((const char*)Uld + ad);
          acc[f] = __builtin_amdgcn_mfma_f32_16x16x32_bf16(a, b, acc[f], 0, 0, 0);
        }
      }
      #pragma unroll
      for(int f=0;f<FR;f++)
        #pragma unroll
        for(int e=0;e<4;e++)
          zp[(w*16 + kg*4 + e)*68 + f*16 + l15] = acc[f][e];
    }
    __syncthreads();
    if(active && tid < ITEMS){
      float4 z0 = *(const float4*)(zp + (     er)*68 + eu*4);
      float4 z1 = *(const float4*)(zp + (16 + er)*68 + eu*4);
      float4 z2 = *(const float4*)(zp + (32 + er)*68 + eu*4);
      float4 z3 = *(const float4*)(zp + (48 + er)*68 + eu*4);
      float si = z0.x+z1.x+z2.x+z3.x + bvr.x;
      float sf = z0.y+z1.y+z2.y+z3.y + bvr.y;
      float sg = z0.z+z1.z+z2.z+z3.z + bvr.z;
      float so = z0.w+z1.w+z2.w+z3.w + bvr.w;
      if constexpr(LAYER == 0){
        float4 xv = *(const float4*)(xw0 + ((size_t)(er*T_ + t))*(4*HU) + base_p + eu*4);
        si += xv.x; sf += xv.y; sg += xv.z; so += xv.w;
      }
      float cin = (t == 0) ? cinit[er*HU + base_u + eu] : creg;
      float c2 = sigm(sf)*cin + sigm(si)*tanhf(sg);
      float h2 = sigm(so)*tanhf(c2);
      creg = c2;
      size_t hrow = TB ? ((size_t)(t*B_ + er)) : ((size_t)(er*T_ + t));
      store_coh16(&hseqW[hrow*HU + base_u + eu], (unsigned)f2bf(h2));
      if(t == T_-1) store_cohf(&cfin[er*HU + base_u + eu], c2);
    }
    if(it < T_) gbar3(bar, (unsigned)(it+1), nblk, det, myblk);
  }
  asm volatile("s_waitcnt vmcnt(0)" ::: "memory");
  __syncthreads();
  if(tid == 0) store_cohu(bar + (size_t)myblk*16, (unsigned)(T_+1));
}

// ------------- mega kernel 1: RNN1 + spares {prep, wpT1w, wpT2w, xw2, proj1}
__global__ __launch_bounds__(256, 1)
void k_rnn1m(const unsigned short* __restrict__ Ut0, const unsigned short* __restrict__ WU1,
    const float* __restrict__ xw0, const float* __restrict__ bpk0, const float* __restrict__ bpk1,
    const unsigned short* __restrict__ h0init, const unsigned short* __restrict__ h1init,
    const float* __restrict__ c0init, const float* __restrict__ c1init,
    unsigned short* __restrict__ h0seq, unsigned short* __restrict__ h1seq,
    float* __restrict__ c0fin, float* __restrict__ c1fin, unsigned* bar,
    const int* __restrict__ ids2, const float* __restrict__ emb, unsigned short* __restrict__ ebuf2,
    const float* __restrict__ b2_0, const float* __restrict__ b2_1,
    float* __restrict__ bpk20, float* __restrict__ bpk21,
    const float* __restrict__ U2_0, unsigned short* __restrict__ ut0_2,
    const float* __restrict__ W2_0, unsigned short* __restrict__ wtmp2,
    const float* __restrict__ W2_1, const float* __restrict__ U2_1, unsigned short* __restrict__ wu1_2,
    const float* __restrict__ Wp1, unsigned short* __restrict__ wpT1,
    const float* __restrict__ Wp2, unsigned short* __restrict__ wpT2,
    const float* __restrict__ bp1, float* __restrict__ out1,
    float* __restrict__ xw2buf, int wide)
{
  constexpr int HU = 512, C0 = 64, C1 = 64;
  constexpr int NB0 = 4*HU/C0;         // 32
  constexpr int NRNN = NB0 + 4*HU/C1;  // 64
  constexpr int NS = 256 - NRNN;       // 192 spare
  __shared__ __align__(16) unsigned short Uld[65536];
  __shared__ __align__(16) float zred[64*68];
  const int blk = blockIdx.x;
  const int tid = threadIdx.x;
  if(blk < NB0){
    rnn_body<C0, HU, 0, HU, 1>(Uld, zred, Ut0 + (size_t)blk*C0*HU, xw0, bpk0,
        h0init, h1init, c0init, h0seq, h1seq, c0fin, bar, blk, NRNN, blk==0, blk);
  } else if(blk < NRNN){
    rnn_body<C1, 2*HU, 1, HU, 1>(Uld, zred, WU1 + (size_t)(blk-NB0)*C1*2*HU, nullptr, bpk1,
        h0init, h1init, c1init, h0seq, h1seq, c1fin, bar, blk-NB0, NRNN, false, blk);
  } else {
    const int q = blk - NRNN;          // 0..191
    float (*tile)[33]   = (float(*)[33])Uld;
    float (*tile2)[257] = (float(*)[257])Uld;
    unsigned short* As = Uld;
    unsigned short* Bs = Uld + 8192;
    volatile int* rdy = (volatile int*)((char*)Uld + 128000);
    // ---- phase 1: prep jobs ----
    const int J0 = 512, J1 = J0+32, J2 = J1+4096, J3 = J2+2048, J4 = J3+4096, J5 = J4+4096;
    const int J6 = J5 + 2000;   // wpT1 wide (K=512: 125 x 16)
    const int J7 = J6 + 4000;   // wpT2 wide (K=1024: 125 x 32)
    const int totJ = wide ? J7 : J5;
    for(int j = q; j < totJ; j += NS){
      if(j < J0){
        int row = j*2 + (tid>>7);
        int id = ids2[row];
        float4 v = *(const float4*)(emb + (size_t)id*E_ + (tid&127)*4);
        ushort4 o; o.x=f2bf(v.x); o.y=f2bf(v.y); o.z=f2bf(v.z); o.w=f2bf(v.w);
        *(ushort4*)(ebuf2 + (size_t)row*E_ + (tid&127)*4) = o;
      } else if(j < J1){
        int jj = j - J0;
        const float* b = (jj < 16) ? b2_0 : b2_1;
        float* o = (jj < 16) ? bpk20 : bpk21;
        int p = (jj & 15)*256 + tid;
        o[p] = b[(p&3)*1024 + (p>>2)];
      } else if(j < J2){
        int r = j - J1; tcvt_dev(U2_0, ut0_2, 4096, 1024, 1024, 0, 1, r%128, r/128, tile);
      } else if(j < J3){
        int r = j - J2; tcvt_dev(W2_0, wtmp2, 4096, 1024, 512, 0, 0, r%128, r/128, tile);
      } else if(j < J4){
        int r = j - J3; tcvt_dev(W2_1, wu1_2, 4096, 1024, 2048, 0, 1, r%128, r/128, tile);
      } else if(j < J5){
        int r = j - J4; tcvt_dev(U2_1, wu1_2, 4096, 1024, 2048, 1024, 1, r%128, r/128, tile);
      } else if(j < J6){
        int r = j - J5; tcvtw_dev(Wp1, wpT1, 32000, 512, r%125, r/125, tile2);
      } else {
        int r = j - J6; tcvtw_dev(Wp2, wpT2, 32000, 1024, r%125, r/125, tile2);
      }
    }
    if(!wide) return;
    // ---- phase 2: cross-XCD visibility + spare barrier ----
    __syncthreads();
    __threadfence();
    if(tid == 0)
      __hip_atomic_fetch_add(bar + 5120, 1u, __ATOMIC_RELAXED, __HIP_MEMORY_SCOPE_AGENT);
    if(tid == 0){
      while(load_coh(bar + 5120) < (unsigned)NS) __builtin_amdgcn_s_sleep(8);
    }
    __syncthreads();
    // ---- phase 2.5: xw2 = ebuf2 @ wtmp2 (hidden, wide2 only) ----
    if(xw2buf){
      for(int t2 = q; t2 < 256; t2 += NS)
        mm_tile(ebuf2, wtmp2, nullptr, xw2buf, 4096, 512, (t2>>5)*128, (t2&31)*128, As, Bs, 0);
    }
    // ---- phase 3: proj1 pipelined against RNN1 L1 progress ----
    for(int g = 0; g < 8; ++g){
      const unsigned req = 8u*(unsigned)g + 9u;
      for(;;){
        if(tid == 0) *rdy = 1;
        __syncthreads();
        if(tid < 32){
          if(load_coh(bar + (size_t)(NB0 + tid)*16) < req) *rdy = 0;
        }
        __syncthreads();
        if(*rdy) break;
        __builtin_amdgcn_s_sleep(16);
      }
      for(int n = q; n < 250; n += NS)
        mm_tile(h1seq, wpT1, bp1, out1, V_, 512, g*128, n*128, As, Bs, 1);
    }
  }
}

// ------------- mega kernel 2: RNN2 + spares {proj2 groups 0..5} ------------
__global__ __launch_bounds__(256, 1)
void k_rnn2m(const unsigned short* __restrict__ Ut0, const unsigned short* __restrict__ WU1,
    const float* __restrict__ xw0, const float* __restrict__ bpk0, const float* __restrict__ bpk1,
    const unsigned short* __restrict__ h0init, const unsigned short* __restrict__ h1init,
    const float* __restrict__ c0init, const float* __restrict__ c1init,
    unsigned short* __restrict__ h0seq, unsigned short* __restrict__ h1seq,
    float* __restrict__ c0fin, float* __restrict__ c1fin, unsigned* bar,
    const unsigned short* __restrict__ wpT2,
    const float* __restrict__ bp2, float* __restrict__ out2, int wide)
{
  constexpr int HU = 1024, C0 = 64, C1 = 32;
  constexpr int NB0 = 4*HU/C0;          // 64
  constexpr int NRNN = NB0 + 4*HU/C1;   // 192
  constexpr int NS = 64;
  __shared__ __align__(16) unsigned short Uld[65536];
  __shared__ __align__(16) float zred[64*68];
  const int blk = blockIdx.x;
  const int tid = threadIdx.x;
  if(blk < NB0){
    rnn_body<C0, HU, 0, HU, 1>(Uld, zred, Ut0 + (size_t)blk*C0*HU, xw0, bpk0,
        h0init, h1init, c0init, h0seq, h1seq, c0fin, bar, blk, NRNN, blk==0, blk);
  } else if(blk < NRNN){
    rnn_body<C1, 2*HU, 1, HU, 1>(Uld, zred, WU1 + (size_t)(blk-NB0)*C1*2*HU, nullptr, bpk1,
        h0init, h1init, c1init, h0seq, h1seq, c1fin, bar, blk-NB0, NRNN, false, blk);
  } else if(wide){
    const int q = blk - NRNN;            // 0..63
    unsigned short* As = Uld;
    unsigned short* Bs = Uld + 8192;
    volatile int* rdy = (volatile int*)((char*)Uld + 128000);
    for(int g = 0; g < 6; ++g){
      const unsigned req = 8u*(unsigned)g + 9u;
      for(;;){
        if(tid == 0) *rdy = 1;
        __syncthreads();
        if(tid < 128){
          if(load_coh(bar + (size_t)(NB0 + tid)*16) < req) *rdy = 0;
        }
        __syncthreads();
        if(*rdy) break;
        __builtin_amdgcn_s_sleep(16);
      }
      for(int n = q; n < 250; n += NS)
        mm_tile(h1seq, wpT2, bp2, out2, V_, 1024, g*128, n*128, As, Bs, 1);
    }
  }
}

// ---------------------------------------------------------------------------
extern "C" void kernel_launch(void* const* d_in, const int* in_sizes, int n_in,
                              void* d_out, int out_size, void* d_ws, size_t ws_size,
                              hipStream_t stream){
  const int*   ids1 = (const int*)d_in[0];
  const int*   ids2 = (const int*)d_in[1];
  const float* init = (const float*)d_in[2];
  const float* emb  = (const float*)d_in[3];
  const float* W1_0 = (const float*)d_in[4];
  const float* U1_0 = (const float*)d_in[5];
  const float* b1_0 = (const float*)d_in[6];
  const float* W1_1 = (const float*)d_in[7];
  const float* U1_1 = (const float*)d_in[8];
  const float* b1_1 = (const float*)d_in[9];
  const float* W2_0 = (const float*)d_in[10];
  const float* U2_0 = (const float*)d_in[11];
  const float* b2_0 = (const float*)d_in[12];
  const float* W2_1 = (const float*)d_in[13];
  const float* U2_1 = (const float*)d_in[14];
  const float* b2_1 = (const float*)d_in[15];
  const float* Wp1  = (const float*)d_in[16];
  const float* bp1  = (const float*)d_in[17];
  const float* Wp2  = (const float*)d_in[18];
  const float* bp2  = (const float*)d_in[19];
  float* out1 = (float*)d_out;
  float* out2 = out1 + (size_t)B_*T_*V_;

  char* base = (char*)d_ws;
  float*          xw    = (float*)(base);                           // 16 MB
  unsigned short* ut0_1 = (unsigned short*)(base + (16u<<20));      // 2 MB
  unsigned short* wu1_1 = (unsigned short*)(base + (18u<<20));      // 4 MB
  unsigned short* ut0_2 = (unsigned short*)(base + (22u<<20));      // 8 MB
  unsigned short* wu1_2 = (unsigned short*)(base + (30u<<20));      // 16 MB
  unsigned short* wtmp  = (unsigned short*)(base + (46u<<20));      // 4 MB
  unsigned short* ebuf  = (unsigned short*)(base + (50u<<20));      // 1 MB
  unsigned short* h0s1  = (unsigned short*)(base + (51u<<20));      // 1 MB  [t*B+b]
  unsigned short* h1s1  = (unsigned short*)(base + (52u<<20));      // 1 MB  [t*B+b]
  unsigned short* h0s2  = (unsigned short*)(base + (53u<<20));      // 2 MB  [t*B+b]
  unsigned short* h1s2  = (unsigned short*)(base + (55u<<20));      // 2 MB  [t*B+b]
  char* M = base + (57u<<20);
  unsigned short* h0i1 = (unsigned short*)(M);
  unsigned short* h1i1 = (unsigned short*)(M + 16384);
  float* c0i1 = (float*)(M + 32768);
  float* c1i1 = (float*)(M + 65536);
  unsigned short* h2i0 = (unsigned short*)(M + 98304);
  unsigned short* h2i1 = (unsigned short*)(M + 131072);
  float* c2i0 = (float*)(M + 163840);
  float* c2i1 = (float*)(M + 229376);
  float* c0f1 = (float*)(M + 294912);
  float* c1f1 = (float*)(M + 327680);
  float* c0f2 = (float*)(M + 360448);
  float* c1f2 = (float*)(M + 425984);
  float* bpk10 = (float*)(M + 491520);
  float* bpk11 = (float*)(M + 499712);
  float* bpk20 = (float*)(M + 507904);
  float* bpk21 = (float*)(M + 524288);
  unsigned* bar1 = (unsigned*)(M + 540672);            // 32 KB
  unsigned* bar2 = (unsigned*)(M + 540672 + 32768);    // 32 KB
  unsigned short* wpT1 = (unsigned short*)(base + (58u<<20));   // 31.25 MiB
  unsigned short* wpT2 = (unsigned short*)(base + (90u<<20));   // 62.5 MiB
  float*          xw2  = (float*)(base + (153u<<20));           // 16 MiB
  const size_t NEED_W  = ((size_t)90u<<20) + (size_t)V_*1024*2;
  const size_t NEED_W2 = ((size_t)169u<<20);
  const bool wide  = ws_size >= NEED_W;
  const bool wide2 = ws_size >= NEED_W2;
  float* xw2p = wide2 ? xw2 : xw;

  k_barinit<<<dim3(64), dim3(256), 0, stream>>>(bar1);

  // ===== RNN1 prep =====
  k_init1<<<dim3(32), dim3(256), 0, stream>>>(init, h0i1, c0i1, h1i1, c1i1);
  k_gather<<<dim3(B_*T_), dim3(128), 0, stream>>>(ids1, emb, ebuf);
  k_tcvt<<<dim3(64, 16), dim3(256), 0, stream>>>(U1_0, ut0_1, 2048, 512, 512, 0, 1);
  k_tcvt<<<dim3(64, 16), dim3(256), 0, stream>>>(W1_0, wtmp,  2048, 512, 512, 0, 0);
  k_tcvt<<<dim3(64, 16), dim3(256), 0, stream>>>(W1_1, wu1_1, 2048, 512, 1024, 0, 1);
  k_tcvt<<<dim3(64, 16), dim3(256), 0, stream>>>(U1_1, wu1_1, 2048, 512, 1024, 512, 1);
  k_bpack<<<dim3(8),  dim3(256), 0, stream>>>(b1_0, bpk10, 512, 2048);
  k_bpack<<<dim3(8),  dim3(256), 0, stream>>>(b1_1, bpk11, 512, 2048);
  k_mm<0><<<dim3(16, 8), dim3(256), 0, stream>>>(ebuf, wtmp, nullptr, xw, 1024, 2048, 512, 0, 0);

  // ===== RNN1 + hidden: prep, wpT1/wpT2 wide-cvt, xw2, pipelined proj1 =====
  k_rnn1m<<<dim3(256), dim3(256), 0, stream>>>(ut0_1, wu1_1, xw, bpk10, bpk11,
      h0i1, h1i1, c0i1, c1i1, h0s1, h1s1, c0f1, c1f1, bar1,
      ids2, emb, ebuf, b2_0, b2_1, bpk20, bpk21,
      U2_0, ut0_2, W2_0, wtmp, W2_1, U2_1, wu1_2,
      Wp1, wpT1, Wp2, wpT2, bp1, out1,
      (wide && wide2) ? xw2 : nullptr, (int)wide);

  if(!wide){
    k_mm<1><<<dim3(250, 8), dim3(256), 0, stream>>>(h1s1, Wp1, bp1, out1, 1024, V_, 512, 1, 0);
  }
  if(!wide || !wide2){
    // serial xw2 (overwrites xw after RNN1 done — safe)
    k_mm<0><<<dim3(32, 8), dim3(256), 0, stream>>>(ebuf, wtmp, nullptr, xw, 1024, 4096, 512, 0, 0);
  }
  k_init2<<<dim3(64, 2), dim3(256), 0, stream>>>(init, h0s1, h1s1, c0f1, c1f1,
                                                 h2i0, h2i1, c2i0, c2i1);

  // ===== RNN2 + hidden: proj2 groups 0..5 =====
  k_rnn2m<<<dim3(256), dim3(256), 0, stream>>>(ut0_2, wu1_2, xw2p, bpk20, bpk21,
      h2i0, h2i1, c2i0, c2i1, h0s2, h1s2, c0f2, c1f2, bar2,
      wpT2, bp2, out2, (int)wide);

  // ===== projection 2 remainder =====
  if(wide){
    k_mm<0><<<dim3(250, 2), dim3(256), 0, stream>>>(h1s2, wpT2, bp2, out2, 1024, V_, 1024, 1, 768);
  } else {
    k_mm<1><<<dim3(250, 8), dim3(256), 0, stream>>>(h1s2, Wp2, bp2, out2, 1024, V_, 1024, 1, 0);
  }
}

// Round 14
// 892.497 us; speedup vs baseline: 1.1587x; 1.1529x over previous
//
#include <hip/hip_runtime.h>
#include <hip/hip_bf16.h>

#define B_ 16
#define T_ 64
#define E_ 512
#define H_ 512
#define V_ 32000

typedef __attribute__((ext_vector_type(4))) float f32x4;
typedef __attribute__((ext_vector_type(8))) short s16x8;

__device__ __forceinline__ float sigm(float x){ return 1.0f/(1.0f + __expf(-x)); }

__device__ __forceinline__ unsigned short f2bf(float x){
  unsigned int u = __float_as_uint(x);
  return (unsigned short)((u + 0x7FFFu + ((u>>16)&1u)) >> 16);
}

// ---- coherence-point ops (no cache-wide writeback/invalidate anywhere) ----
__device__ __forceinline__ unsigned load_coh(const unsigned* p){
  unsigned v;
  asm volatile("global_load_dword %0, %1, off sc0 sc1\n\ts_waitcnt vmcnt(0)"
               : "=v"(v) : "v"(p) : "memory");
  return v;
}
__device__ __forceinline__ void store_coh16(unsigned short* p, unsigned v){
  asm volatile("global_store_short %0, %1, off sc0 sc1" :: "v"(p), "v"(v) : "memory");
}
__device__ __forceinline__ void store_cohf(float* p, float v){
  asm volatile("global_store_dword %0, %1, off sc0 sc1" :: "v"(p), "v"(v) : "memory");
}
__device__ __forceinline__ void store_cohu(unsigned* p, unsigned v){
  asm volatile("global_store_dword %0, %1, off sc0 sc1" :: "v"(p), "v"(v) : "memory");
}

// ---- grid barrier: RMW-free flags + detector; gen sharded on 8 lines ------
__device__ __forceinline__ void gbar3(unsigned* barb, unsigned bi1, int nblk,
                                      bool det, int myblk){
  asm volatile("s_waitcnt vmcnt(0)" ::: "memory");
  __syncthreads();
  const int tid = threadIdx.x;
  if(tid == 0) store_cohu(barb + (size_t)myblk*16, bi1);
  if(det){
    if(tid < nblk){
      const unsigned* fp = barb + (size_t)tid*16;
      while(load_coh(fp) < bi1) __builtin_amdgcn_s_sleep(1);
    }
    __syncthreads();
    if(tid < 8) store_cohu(barb + 4096 + (size_t)tid*16, bi1);
  } else {
    if(tid == 0){
      const unsigned* gp = barb + 4096 + (size_t)(myblk & 7)*16;
      while(load_coh(gp) < bi1) __builtin_amdgcn_s_sleep(1);
    }
  }
  __syncthreads();
}

__global__ void k_barinit(unsigned* bar){
  int i = blockIdx.x*256 + threadIdx.x;
  if(i < 16384) bar[i] = 0u;
}

// ------------- embedding gather -> bf16 ------------------------------------
__global__ void k_gather(const int* __restrict__ ids, const float* __restrict__ emb,
                         unsigned short* __restrict__ out){
  const int row = blockIdx.x;
  const int id  = ids[row];
  float4 v = *(const float4*)(emb + (size_t)id*E_ + threadIdx.x*4);
  ushort4 o;
  o.x = f2bf(v.x); o.y = f2bf(v.y); o.z = f2bf(v.z); o.w = f2bf(v.w);
  *(ushort4*)(out + (size_t)row*E_ + threadIdx.x*4) = o;
}

// ------------- transpose+convert(+permute)(+swizzle), 32x32 tile -----------
__device__ __forceinline__ void tcvt_dev(const float* __restrict__ in,
    unsigned short* __restrict__ out, int N, int Hp, int Kfull, int koff, int swz,
    int bx, int by, float (*tile)[33]){
  const int n0 = bx*32, k0 = by*32;
  const int x = threadIdx.x & 31, y = threadIdx.x >> 5;
  __syncthreads();
  #pragma unroll
  for(int i=0;i<4;i++){
    int k = y + i*8;
    tile[k][x] = in[(size_t)(k0+k)*N + n0 + x];
  }
  __syncthreads();
  #pragma unroll
  for(int i=0;i<4;i++){
    int nl = y + i*8;
    int n  = n0 + nl;
    int p  = Hp ? ((n % Hp)*4 + n / Hp) : n;
    int kk = koff + k0 + x;
    size_t idx;
    if(swz){
      int k2 = kk*2;
      int slot = ((k2>>4)&7) ^ (p&7);
      idx = (size_t)p*Kfull + (((k2 & ~127) | (slot<<4) | (k2 & 15)) >> 1);
    } else {
      idx = (size_t)p*Kfull + kk;
    }
    out[idx] = f2bf(tile[x][nl]);
  }
}

__global__ __launch_bounds__(256)
void k_tcvt(const float* __restrict__ in, unsigned short* __restrict__ out,
            int N, int Hp, int Kfull, int koff, int swz){
  __shared__ float tile[32][33];
  tcvt_dev(in, out, N, Hp, Kfull, koff, swz, blockIdx.x, blockIdx.y, tile);
}

// ------------- WIDE transpose-cvt: 32 k-rows x 256 n-cols per call ---------
__device__ __forceinline__ void tcvtw_dev(const float* __restrict__ in,
    unsigned short* __restrict__ out, int N, int K, int bx, int by,
    float (*tile)[257]){
  const int tid = threadIdx.x;
  const int n0 = bx*256, k0 = by*32;
  const int row = tid >> 3, nc = (tid & 7)*32;
  __syncthreads();
  #pragma unroll
  for(int j=0;j<8;j++){
    float4 v = *(const float4*)(in + (size_t)(k0+row)*N + n0 + nc + j*4);
    *(float4*)&tile[row][nc + j*4] = v;
  }
  __syncthreads();
  __align__(16) unsigned short vals[32];
  #pragma unroll
  for(int k=0;k<32;k++) vals[k] = f2bf(tile[k][tid]);
  unsigned short* op = out + (size_t)(n0+tid)*K + k0;
  #pragma unroll
  for(int j=0;j<4;j++)
    *(uint4*)(op + j*8) = *(const uint4*)&vals[j*8];
}

// ------------- bias permute -------------------------------------------------
__global__ void k_bpack(const float* __restrict__ b, float* __restrict__ out, int H, int N){
  int p = blockIdx.x*256 + threadIdx.x;
  if(p < N) out[p] = b[(p&3)*H + (p>>2)];
}

// ------------- init states --------------------------------------------------
__global__ void k_init1(const float* __restrict__ init_state,
                        unsigned short* h0i, float* c0i, unsigned short* h1i, float* c1i){
  int i = blockIdx.x*256 + threadIdx.x;
  if(i >= B_*H_) return;
  float v0 = init_state[i];
  float v1 = init_state[B_*H_ + i];
  h0i[i] = f2bf(v0); c0i[i] = v0;
  h1i[i] = f2bf(v1); c1i[i] = v1;
}

// h0seq1/h1seq1 are T-MAJOR ([t*B+b]) — final row at t=63.
__global__ void k_init2(const float* __restrict__ init_state,
                        const unsigned short* __restrict__ h0seq1,
                        const unsigned short* __restrict__ h1seq1,
                        const float* __restrict__ c0f1, const float* __restrict__ c1f1,
                        unsigned short* h20i, unsigned short* h21i,
                        float* c20i, float* c21i){
  const int l = blockIdx.y;
  int i = blockIdx.x*256 + threadIdx.x;
  if(i >= B_*2*H_) return;
  const int r = i >> 10, j = i & 1023;
  unsigned short* ho = l ? h21i : h20i;
  float* co = l ? c21i : c20i;
  if(j < H_){
    float v = init_state[(size_t)l*B_*H_ + r*H_ + j];
    ho[i] = f2bf(v); co[i] = v;
  } else {
    const unsigned short* hs = l ? h1seq1 : h0seq1;
    const float* cf = l ? c1f1 : c0f1;
    ho[i] = hs[(size_t)((T_-1)*B_ + r)*H_ + (j - H_)];
    co[i] = cf[r*H_ + (j - H_)];
  }
}

// ------------- MFMA GEMM tile (B pre-transposed bf16); optional row remap --
__device__ __forceinline__ void mm_tile(const unsigned short* __restrict__ A,
    const unsigned short* __restrict__ Bt, const float* __restrict__ bias,
    float* __restrict__ C, int N, int K, int bm, int bn,
    unsigned short* As, unsigned short* Bs, int remap){
  const int tid = threadIdx.x;
  const int lane = tid & 63, w = tid >> 6;
  const int wm = (w>>1)*64, wn = (w&1)*64;
  const int l15 = lane & 15, kg = lane >> 4;
  f32x4 acc[4][4] = {};
  for(int k0=0; k0<K; k0+=64){
    __syncthreads();
    #pragma unroll
    for(int ch=0; ch<4; ch++){
      int off = ch*4096 + tid*16;
      int row = off >> 7;
      int s   = ((off >> 4) & 7) ^ (row & 7);
      __builtin_amdgcn_global_load_lds(
        (const __attribute__((address_space(1))) unsigned int*)(A + (size_t)(bm+row)*K + k0 + s*8),
        (__attribute__((address_space(3))) unsigned int*)((char*)As + off), 16, 0, 0);
    }
    #pragma unroll
    for(int ch=0; ch<4; ch++){
      int off = ch*4096 + tid*16;
      int row = off >> 7;
      int s   = ((off >> 4) & 7) ^ (row & 7);
      __builtin_amdgcn_global_load_lds(
        (const __attribute__((address_space(1))) unsigned int*)(Bt + (size_t)(bn+row)*K + k0 + s*8),
        (__attribute__((address_space(3))) unsigned int*)((char*)Bs + off), 16, 0, 0);
    }
    __syncthreads();
    #pragma unroll
    for(int q=0;q<2;q++){
      s16x8 af[4], bf[4];
      #pragma unroll
      for(int mt=0;mt<4;mt++){
        int row = wm + mt*16 + l15;
        int s = (q*4 + kg) ^ (row & 7);
        af[mt] = *(const s16x8*)(As + row*64 + s*8);
      }
      #pragma unroll
      for(int nt=0;nt<4;nt++){
        int row = wn + nt*16 + l15;
        int s = (q*4 + kg) ^ (row & 7);
        bf[nt] = *(const s16x8*)(Bs + row*64 + s*8);
      }
      #pragma unroll
      for(int mt=0;mt<4;mt++)
        #pragma unroll
        for(int nt=0;nt<4;nt++)
          acc[mt][nt] = __builtin_amdgcn_mfma_f32_16x16x32_bf16(af[mt], bf[nt], acc[mt][nt], 0, 0, 0);
    }
  }
  #pragma unroll
  for(int mt=0;mt<4;mt++){
    #pragma unroll
    for(int nt=0;nt<4;nt++){
      int col = bn + wn + nt*16 + l15;
      float bv = bias ? bias[col] : 0.f;
      #pragma unroll
      for(int e=0;e<4;e++){
        int row = bm + wm + mt*16 + kg*4 + e;
        int orow = remap ? ((row & 15)*T_ + (row >> 4)) : row;
        C[(size_t)orow*N + col] = acc[mt][nt][e] + bv;
      }
    }
  }
}

// ------------- standalone MFMA GEMM kernel (bm0 = row offset) --------------
template<int BF32>
__global__ __launch_bounds__(256)
void k_mm(const unsigned short* __restrict__ A, const void* __restrict__ Bsrc,
          const float* __restrict__ bias, float* __restrict__ C,
          int M, int N, int K, int remap, int bm0){
  __shared__ __align__(16) unsigned short As[128*64];
  __shared__ __align__(16) unsigned short Bs[128*64];
  if(!BF32){
    mm_tile(A, (const unsigned short*)Bsrc, bias, C, N, K,
            bm0 + blockIdx.y*128, blockIdx.x*128, As, Bs, remap);
    return;
  }
  const int tid = threadIdx.x;
  const int lane = tid & 63, w = tid >> 6;
  const int wm = (w>>1)*64, wn = (w&1)*64;
  const int bm = bm0 + blockIdx.y*128, bn = blockIdx.x*128;
  const int l15 = lane & 15, kg = lane >> 4;
  f32x4 acc[4][4] = {};
  for(int k0=0; k0<K; k0+=64){
    __syncthreads();
    #pragma unroll
    for(int ch=0; ch<4; ch++){
      int off = ch*4096 + tid*16;
      int row = off >> 7;
      int s   = ((off >> 4) & 7) ^ (row & 7);
      __builtin_amdgcn_global_load_lds(
        (const __attribute__((address_space(1))) unsigned int*)(A + (size_t)(bm+row)*K + k0 + s*8),
        (__attribute__((address_space(3))) unsigned int*)((char*)As + off), 16, 0, 0);
    }
    {
      const float* Bf = (const float*)Bsrc;
      #pragma unroll
      for(int i=0;i<8;i++){
        int kl = (tid>>5) + i*8;
        int nl = (tid&31)*4;
        float4 v = *(const float4*)(Bf + (size_t)(k0+kl)*N + bn + nl);
        int slot = kl >> 3, kb = kl & 7;
        float vv[4] = {v.x, v.y, v.z, v.w};
        #pragma unroll
        for(int jj=0;jj<4;jj++){
          int n = nl + jj;
          Bs[n*64 + ((slot ^ (n&7))*8) + kb] = f2bf(vv[jj]);
        }
      }
    }
    __syncthreads();
    #pragma unroll
    for(int q=0;q<2;q++){
      s16x8 af[4], bf[4];
      #pragma unroll
      for(int mt=0;mt<4;mt++){
        int row = wm + mt*16 + l15;
        int s = (q*4 + kg) ^ (row & 7);
        af[mt] = *(const s16x8*)(As + row*64 + s*8);
      }
      #pragma unroll
      for(int nt=0;nt<4;nt++){
        int row = wn + nt*16 + l15;
        int s = (q*4 + kg) ^ (row & 7);
        bf[nt] = *(const s16x8*)(Bs + row*64 + s*8);
      }
      #pragma unroll
      for(int mt=0;mt<4;mt++)
        #pragma unroll
        for(int nt=0;nt<4;nt++)
          acc[mt][nt] = __builtin_amdgcn_mfma_f32_16x16x32_bf16(af[mt], bf[nt], acc[mt][nt], 0, 0, 0);
    }
  }
  #pragma unroll
  for(int mt=0;mt<4;mt++){
    #pragma unroll
    for(int nt=0;nt<4;nt++){
      int col = bn + wn + nt*16 + l15;
      float bv = bias ? bias[col] : 0.f;
      #pragma unroll
      for(int e=0;e<4;e++){
        int row = bm + wm + mt*16 + kg*4 + e;
        int orow = remap ? ((row & 15)*T_ + (row >> 4)) : row;
        C[(size_t)orow*N + col] = acc[mt][nt][e] + bv;
      }
    }
  }
}

// ------------- persistent 2-layer LSTM body; TB=1 -> t-major hseq ----------
template<int C, int K, int LAYER, int HU, int TB>
__device__ __forceinline__ void rnn_body(
    unsigned short* __restrict__ Uld, float* __restrict__ zp,
    const unsigned short* __restrict__ Uslice,
    const float* __restrict__ xw0, const float* __restrict__ bpk,
    const unsigned short* __restrict__ h0init, const unsigned short* __restrict__ h1init,
    const float* __restrict__ cinit,
    unsigned short* __restrict__ h0seq, unsigned short* __restrict__ h1seq,
    float* __restrict__ cfin, unsigned* bar, int cb, int nblk, bool det, int myblk)
{
  constexpr int KW = K/4, KS = KW/32, FR = C/16, UB = C/4;
  constexpr int K2 = K*2;
  constexpr int ITEMS = 16*UB;
  const int tid = threadIdx.x;
  const int lane = tid & 63, w = tid >> 6;
  const int l15 = lane & 15, kg = lane >> 4;

  constexpr int CP = (C*K2)/4096;
  #pragma unroll
  for(int i=0;i<CP;i++){
    __builtin_amdgcn_global_load_lds(
      (const __attribute__((address_space(1))) unsigned int*)((const char*)Uslice + i*4096 + tid*16),
      (__attribute__((address_space(3))) unsigned int*)((char*)Uld + i*4096 + tid*16), 16, 0, 0);
  }
  const int base_p = cb*C;
  const int base_u = cb*UB;
  float4 bvr = make_float4(0.f,0.f,0.f,0.f);
  int er = 0, eu = 0;
  if(tid < ITEMS){ er = tid / UB; eu = tid - er*UB; bvr = *(const float4*)(bpk + base_p + eu*4); }
  float creg = 0.f;
  unsigned short* hseqW = LAYER ? h1seq : h0seq;

  int cbyte[FR], cx[FR];
  #pragma unroll
  for(int f=0;f<FR;f++){ int c = f*16 + l15; cbyte[f] = c*K2; cx[f] = (c&7)<<4; }

  __syncthreads();

  for(int it = 0; it <= T_; ++it){
    const bool active = LAYER ? (it >= 1) : (it < T_);
    const int t = LAYER ? it-1 : it;
    if(active){
      const unsigned short* asrc;
      if constexpr(LAYER == 0){
        asrc = (t == 0) ? (h0init + l15*HU)
             : (h0seq + ((size_t)(TB ? ((t-1)*B_ + l15) : (l15*T_ + (t-1))))*HU);
      } else {
        if(w < 2){
          asrc = h0seq + ((size_t)(TB ? (t*B_ + l15) : (l15*T_ + t)))*HU;
        } else {
          asrc = ((t == 0) ? (h1init + l15*HU)
               : (h1seq + ((size_t)(TB ? ((t-1)*B_ + l15) : (l15*T_ + (t-1))))*HU)) - HU;
        }
      }
      f32x4 acc[FR];
      #pragma unroll
      for(int f=0;f<FR;f++) acc[f] = (f32x4){0.f,0.f,0.f,0.f};
      #pragma unroll
      for(int s=0;s<KS;s++){
        const int kel = w*KW + s*32 + kg*8;
        s16x8 a = *(const s16x8*)(asrc + kel);
        const int kb  = kel*2;
        const int kch = kb & ~127;
        const int ksl = (kb >> 4) & 7;
        #pragma unroll
        for(int f=0;f<FR;f++){
          const int ad = cbyte[f] + kch + ((ksl<<4) ^ cx[f]);
          s16x8 b = *(const s16x8*)((const char*)Uld + ad);
          acc[f] = __builtin_amdgcn_mfma_f32_16x16x32_bf16(a, b, acc[f], 0, 0, 0);
        }
      }
      #pragma unroll
      for(int f=0;f<FR;f++)
        #pragma unroll
        for(int e=0;e<4;e++)
          zp[(w*16 + kg*4 + e)*68 + f*16 + l15] = acc[f][e];
    }
    __syncthreads();
    if(active && tid < ITEMS){
      float4 z0 = *(const float4*)(zp + (     er)*68 + eu*4);
      float4 z1 = *(const float4*)(zp + (16 + er)*68 + eu*4);
      float4 z2 = *(const float4*)(zp + (32 + er)*68 + eu*4);
      float4 z3 = *(const float4*)(zp + (48 + er)*68 + eu*4);
      float si = z0.x+z1.x+z2.x+z3.x + bvr.x;
      float sf = z0.y+z1.y+z2.y+z3.y + bvr.y;
      float sg = z0.z+z1.z+z2.z+z3.z + bvr.z;
      float so = z0.w+z1.w+z2.w+z3.w + bvr.w;
      if constexpr(LAYER == 0){
        float4 xv = *(const float4*)(xw0 + ((size_t)(er*T_ + t))*(4*HU) + base_p + eu*4);
        si += xv.x; sf += xv.y; sg += xv.z; so += xv.w;
      }
      float cin = (t == 0) ? cinit[er*HU + base_u + eu] : creg;
      float c2 = sigm(sf)*cin + sigm(si)*tanhf(sg);
      float h2 = sigm(so)*tanhf(c2);
      creg = c2;
      size_t hrow = TB ? ((size_t)(t*B_ + er)) : ((size_t)(er*T_ + t));
      store_coh16(&hseqW[hrow*HU + base_u + eu], (unsigned)f2bf(h2));
      if(t == T_-1) store_cohf(&cfin[er*HU + base_u + eu], c2);
    }
    if(it < T_) gbar3(bar, (unsigned)(it+1), nblk, det, myblk);
  }
  asm volatile("s_waitcnt vmcnt(0)" ::: "memory");
  __syncthreads();
  if(tid == 0) store_cohu(bar + (size_t)myblk*16, (unsigned)(T_+1));
}

// ------------- mega kernel 1: RNN1 + spares {prep, wpT1w, wpT2w, xw2, proj1}
__global__ __launch_bounds__(256, 1)
void k_rnn1m(const unsigned short* __restrict__ Ut0, const unsigned short* __restrict__ WU1,
    const float* __restrict__ xw0, const float* __restrict__ bpk0, const float* __restrict__ bpk1,
    const unsigned short* __restrict__ h0init, const unsigned short* __restrict__ h1init,
    const float* __restrict__ c0init, const float* __restrict__ c1init,
    unsigned short* __restrict__ h0seq, unsigned short* __restrict__ h1seq,
    float* __restrict__ c0fin, float* __restrict__ c1fin, unsigned* bar,
    const int* __restrict__ ids2, const float* __restrict__ emb, unsigned short* __restrict__ ebuf2,
    const float* __restrict__ b2_0, const float* __restrict__ b2_1,
    float* __restrict__ bpk20, float* __restrict__ bpk21,
    const float* __restrict__ U2_0, unsigned short* __restrict__ ut0_2,
    const float* __restrict__ W2_0, unsigned short* __restrict__ wtmp2,
    const float* __restrict__ W2_1, const float* __restrict__ U2_1, unsigned short* __restrict__ wu1_2,
    const float* __restrict__ Wp1, unsigned short* __restrict__ wpT1,
    const float* __restrict__ Wp2, unsigned short* __restrict__ wpT2,
    const float* __restrict__ bp1, float* __restrict__ out1,
    float* __restrict__ xw2buf, int wide)
{
  constexpr int HU = 512, C0 = 64, C1 = 64;
  constexpr int NB0 = 4*HU/C0;         // 32
  constexpr int NRNN = NB0 + 4*HU/C1;  // 64
  constexpr int NS = 256 - NRNN;       // 192 spare
  __shared__ __align__(16) unsigned short Uld[65536];
  __shared__ __align__(16) float zred[64*68];
  const int blk = blockIdx.x;
  const int tid = threadIdx.x;
  if(blk < NB0){
    rnn_body<C0, HU, 0, HU, 1>(Uld, zred, Ut0 + (size_t)blk*C0*HU, xw0, bpk0,
        h0init, h1init, c0init, h0seq, h1seq, c0fin, bar, blk, NRNN, blk==0, blk);
  } else if(blk < NRNN){
    rnn_body<C1, 2*HU, 1, HU, 1>(Uld, zred, WU1 + (size_t)(blk-NB0)*C1*2*HU, nullptr, bpk1,
        h0init, h1init, c1init, h0seq, h1seq, c1fin, bar, blk-NB0, NRNN, false, blk);
  } else {
    const int q = blk - NRNN;          // 0..191
    float (*tile)[33]   = (float(*)[33])Uld;
    float (*tile2)[257] = (float(*)[257])Uld;
    unsigned short* As = Uld;
    unsigned short* Bs = Uld + 8192;
    volatile int* rdy = (volatile int*)((char*)Uld + 128000);
    // ---- phase 1: prep jobs ----
    const int J0 = 512, J1 = J0+32, J2 = J1+4096, J3 = J2+2048, J4 = J3+4096, J5 = J4+4096;
    const int J6 = J5 + 2000;   // wpT1 wide (K=512: 125 x 16)
    const int J7 = J6 + 4000;   // wpT2 wide (K=1024: 125 x 32)
    const int totJ = wide ? J7 : J5;
    for(int j = q; j < totJ; j += NS){
      if(j < J0){
        int row = j*2 + (tid>>7);
        int id = ids2[row];
        float4 v = *(const float4*)(emb + (size_t)id*E_ + (tid&127)*4);
        ushort4 o; o.x=f2bf(v.x); o.y=f2bf(v.y); o.z=f2bf(v.z); o.w=f2bf(v.w);
        *(ushort4*)(ebuf2 + (size_t)row*E_ + (tid&127)*4) = o;
      } else if(j < J1){
        int jj = j - J0;
        const float* b = (jj < 16) ? b2_0 : b2_1;
        float* o = (jj < 16) ? bpk20 : bpk21;
        int p = (jj & 15)*256 + tid;
        o[p] = b[(p&3)*1024 + (p>>2)];
      } else if(j < J2){
        int r = j - J1; tcvt_dev(U2_0, ut0_2, 4096, 1024, 1024, 0, 1, r%128, r/128, tile);
      } else if(j < J3){
        int r = j - J2; tcvt_dev(W2_0, wtmp2, 4096, 1024, 512, 0, 0, r%128, r/128, tile);
      } else if(j < J4){
        int r = j - J3; tcvt_dev(W2_1, wu1_2, 4096, 1024, 2048, 0, 1, r%128, r/128, tile);
      } else if(j < J5){
        int r = j - J4; tcvt_dev(U2_1, wu1_2, 4096, 1024, 2048, 1024, 1, r%128, r/128, tile);
      } else if(j < J6){
        int r = j - J5; tcvtw_dev(Wp1, wpT1, 32000, 512, r%125, r/125, tile2);
      } else {
        int r = j - J6; tcvtw_dev(Wp2, wpT2, 32000, 1024, r%125, r/125, tile2);
      }
    }
    if(!wide) return;
    // ---- phase 2: cross-XCD visibility + spare barrier ----
    __syncthreads();
    __threadfence();
    if(tid == 0)
      __hip_atomic_fetch_add(bar + 5120, 1u, __ATOMIC_RELAXED, __HIP_MEMORY_SCOPE_AGENT);
    if(tid == 0){
      while(load_coh(bar + 5120) < (unsigned)NS) __builtin_amdgcn_s_sleep(8);
    }
    __syncthreads();
    // ---- phase 2.5: xw2 = ebuf2 @ wtmp2 (hidden, wide2 only) ----
    if(xw2buf){
      for(int t2 = q; t2 < 256; t2 += NS)
        mm_tile(ebuf2, wtmp2, nullptr, xw2buf, 4096, 512, (t2>>5)*128, (t2&31)*128, As, Bs, 0);
    }
    // ---- phase 3: proj1 pipelined against RNN1 L1 progress ----
    for(int g = 0; g < 8; ++g){
      const unsigned req = 8u*(unsigned)g + 9u;
      for(;;){
        if(tid == 0) *rdy = 1;
        __syncthreads();
        if(tid < 32){
          if(load_coh(bar + (size_t)(NB0 + tid)*16) < req) *rdy = 0;
        }
        __syncthreads();
        if(*rdy) break;
        __builtin_amdgcn_s_sleep(16);
      }
      for(int n = q; n < 250; n += NS)
        mm_tile(h1seq, wpT1, bp1, out1, V_, 512, g*128, n*128, As, Bs, 1);
    }
  }
}

// ------------- pure RNN2 kernel (grid 192) ---------------------------------
template<int HU, int C0, int C1>
__global__ __launch_bounds__(256, 1)
void k_rnn(const unsigned short* __restrict__ Ut0, const unsigned short* __restrict__ WU1,
           const float* __restrict__ xw0, const float* __restrict__ bpk0, const float* __restrict__ bpk1,
           const unsigned short* __restrict__ h0init, const unsigned short* __restrict__ h1init,
           const float* __restrict__ c0init, const float* __restrict__ c1init,
           unsigned short* __restrict__ h0seq, unsigned short* __restrict__ h1seq,
           float* __restrict__ c0fin, float* __restrict__ c1fin, unsigned* bar)
{
  constexpr int NB0 = 4*HU/C0;
  constexpr int UMAXE = (C0*HU > C1*2*HU) ? C0*HU : C1*2*HU;
  __shared__ __align__(16) unsigned short Uld[UMAXE];
  __shared__ __align__(16) float zred[64*68];
  const int nblk = gridDim.x;
  const bool det = (blockIdx.x == 0);
  const int blk = blockIdx.x;
  if(blk < NB0)
    rnn_body<C0, HU, 0, HU, 1>(Uld, zred, Ut0 + (size_t)blk*C0*HU, xw0, bpk0,
                               h0init, h1init, c0init, h0seq, h1seq, c0fin, bar, blk, nblk, det, blk);
  else
    rnn_body<C1, 2*HU, 1, HU, 1>(Uld, zred, WU1 + (size_t)(blk-NB0)*C1*2*HU, nullptr, bpk1,
                               h0init, h1init, c1init, h0seq, h1seq, c1fin, bar, blk-NB0, nblk, det, blk);
}

// ---------------------------------------------------------------------------
extern "C" void kernel_launch(void* const* d_in, const int* in_sizes, int n_in,
                              void* d_out, int out_size, void* d_ws, size_t ws_size,
                              hipStream_t stream){
  const int*   ids1 = (const int*)d_in[0];
  const int*   ids2 = (const int*)d_in[1];
  const float* init = (const float*)d_in[2];
  const float* emb  = (const float*)d_in[3];
  const float* W1_0 = (const float*)d_in[4];
  const float* U1_0 = (const float*)d_in[5];
  const float* b1_0 = (const float*)d_in[6];
  const float* W1_1 = (const float*)d_in[7];
  const float* U1_1 = (const float*)d_in[8];
  const float* b1_1 = (const float*)d_in[9];
  const float* W2_0 = (const float*)d_in[10];
  const float* U2_0 = (const float*)d_in[11];
  const float* b2_0 = (const float*)d_in[12];
  const float* W2_1 = (const float*)d_in[13];
  const float* U2_1 = (const float*)d_in[14];
  const float* b2_1 = (const float*)d_in[15];
  const float* Wp1  = (const float*)d_in[16];
  const float* bp1  = (const float*)d_in[17];
  const float* Wp2  = (const float*)d_in[18];
  const float* bp2  = (const float*)d_in[19];
  float* out1 = (float*)d_out;
  float* out2 = out1 + (size_t)B_*T_*V_;

  char* base = (char*)d_ws;
  float*          xw    = (float*)(base);                           // 16 MB
  unsigned short* ut0_1 = (unsigned short*)(base + (16u<<20));      // 2 MB
  unsigned short* wu1_1 = (unsigned short*)(base + (18u<<20));      // 4 MB
  unsigned short* ut0_2 = (unsigned short*)(base + (22u<<20));      // 8 MB
  unsigned short* wu1_2 = (unsigned short*)(base + (30u<<20));      // 16 MB
  unsigned short* wtmp  = (unsigned short*)(base + (46u<<20));      // 4 MB
  unsigned short* ebuf  = (unsigned short*)(base + (50u<<20));      // 1 MB
  unsigned short* h0s1  = (unsigned short*)(base + (51u<<20));      // 1 MB  [t*B+b]
  unsigned short* h1s1  = (unsigned short*)(base + (52u<<20));      // 1 MB  [t*B+b]
  unsigned short* h0s2  = (unsigned short*)(base + (53u<<20));      // 2 MB  [t*B+b]
  unsigned short* h1s2  = (unsigned short*)(base + (55u<<20));      // 2 MB  [t*B+b]
  char* M = base + (57u<<20);
  unsigned short* h0i1 = (unsigned short*)(M);
  unsigned short* h1i1 = (unsigned short*)(M + 16384);
  float* c0i1 = (float*)(M + 32768);
  float* c1i1 = (float*)(M + 65536);
  unsigned short* h2i0 = (unsigned short*)(M + 98304);
  unsigned short* h2i1 = (unsigned short*)(M + 131072);
  float* c2i0 = (float*)(M + 163840);
  float* c2i1 = (float*)(M + 229376);
  float* c0f1 = (float*)(M + 294912);
  float* c1f1 = (float*)(M + 327680);
  float* c0f2 = (float*)(M + 360448);
  float* c1f2 = (float*)(M + 425984);
  float* bpk10 = (float*)(M + 491520);
  float* bpk11 = (float*)(M + 499712);
  float* bpk20 = (float*)(M + 507904);
  float* bpk21 = (float*)(M + 524288);
  unsigned* bar1 = (unsigned*)(M + 540672);            // 32 KB
  unsigned* bar2 = (unsigned*)(M + 540672 + 32768);    // 32 KB
  unsigned short* wpT1 = (unsigned short*)(base + (58u<<20));   // 31.25 MiB
  unsigned short* wpT2 = (unsigned short*)(base + (90u<<20));   // 62.5 MiB
  float*          xw2  = (float*)(base + (153u<<20));           // 16 MiB
  const size_t NEED_W  = ((size_t)90u<<20) + (size_t)V_*1024*2;
  const size_t NEED_W2 = ((size_t)169u<<20);
  const bool wide  = ws_size >= NEED_W;
  const bool wide2 = ws_size >= NEED_W2;
  float* xw2p = (wide && wide2) ? xw2 : xw;

  k_barinit<<<dim3(64), dim3(256), 0, stream>>>(bar1);

  // ===== RNN1 prep =====
  k_init1<<<dim3(32), dim3(256), 0, stream>>>(init, h0i1, c0i1, h1i1, c1i1);
  k_gather<<<dim3(B_*T_), dim3(128), 0, stream>>>(ids1, emb, ebuf);
  k_tcvt<<<dim3(64, 16), dim3(256), 0, stream>>>(U1_0, ut0_1, 2048, 512, 512, 0, 1);
  k_tcvt<<<dim3(64, 16), dim3(256), 0, stream>>>(W1_0, wtmp,  2048, 512, 512, 0, 0);
  k_tcvt<<<dim3(64, 16), dim3(256), 0, stream>>>(W1_1, wu1_1, 2048, 512, 1024, 0, 1);
  k_tcvt<<<dim3(64, 16), dim3(256), 0, stream>>>(U1_1, wu1_1, 2048, 512, 1024, 512, 1);
  k_bpack<<<dim3(8),  dim3(256), 0, stream>>>(b1_0, bpk10, 512, 2048);
  k_bpack<<<dim3(8),  dim3(256), 0, stream>>>(b1_1, bpk11, 512, 2048);
  k_mm<0><<<dim3(16, 8), dim3(256), 0, stream>>>(ebuf, wtmp, nullptr, xw, 1024, 2048, 512, 0, 0);

  // ===== RNN1 + hidden: prep, wpT1/wpT2 wide-cvt, xw2, pipelined proj1 =====
  k_rnn1m<<<dim3(256), dim3(256), 0, stream>>>(ut0_1, wu1_1, xw, bpk10, bpk11,
      h0i1, h1i1, c0i1, c1i1, h0s1, h1s1, c0f1, c1f1, bar1,
      ids2, emb, ebuf, b2_0, b2_1, bpk20, bpk21,
      U2_0, ut0_2, W2_0, wtmp, W2_1, U2_1, wu1_2,
      Wp1, wpT1, Wp2, wpT2, bp1, out1,
      (wide && wide2) ? xw2 : nullptr, (int)wide);

  if(!wide){
    k_mm<1><<<dim3(250, 8), dim3(256), 0, stream>>>(h1s1, Wp1, bp1, out1, 1024, V_, 512, 1, 0);
  }
  if(!wide || !wide2){
    // serial xw2 (overwrites xw after RNN1 done — safe)
    k_mm<0><<<dim3(32, 8), dim3(256), 0, stream>>>(ebuf, wtmp, nullptr, xw, 1024, 4096, 512, 0, 0);
  }
  k_init2<<<dim3(64, 2), dim3(256), 0, stream>>>(init, h0s1, h1s1, c0f1, c1f1,
                                                 h2i0, h2i1, c2i0, c2i1);

  // ===== pure RNN2 =====
  k_rnn<1024, 64, 32><<<dim3(192), dim3(256), 0, stream>>>(ut0_2, wu1_2, xw2p, bpk20, bpk21,
      h2i0, h2i1, c2i0, c2i1, h0s2, h1s2, c0f2, c1f2, bar2);

  // ===== projection 2 (full, serial) =====
  if(wide){
    k_mm<0><<<dim3(250, 8), dim3(256), 0, stream>>>(h1s2, wpT2, bp2, out2, 1024, V_, 1024, 1, 0);
  } else {
    k_mm<1><<<dim3(250, 8), dim3(256), 0, stream>>>(h1s2, Wp2, bp2, out2, 1024, V_, 1024, 1, 0);
  }
}

// Round 15
// 872.127 us; speedup vs baseline: 1.1858x; 1.0234x over previous
//
#include <hip/hip_runtime.h>
#include <hip/hip_bf16.h>

#define B_ 16
#define T_ 64
#define E_ 512
#define H_ 512
#define V_ 32000

typedef __attribute__((ext_vector_type(4))) float f32x4;
typedef __attribute__((ext_vector_type(8))) short s16x8;

__device__ __forceinline__ float sigm(float x){ return 1.0f/(1.0f + __expf(-x)); }

__device__ __forceinline__ unsigned short f2bf(float x){
  unsigned int u = __float_as_uint(x);
  return (unsigned short)((u + 0x7FFFu + ((u>>16)&1u)) >> 16);
}

// ---- coherence-point ops (no cache-wide writeback/invalidate anywhere) ----
__device__ __forceinline__ unsigned load_coh(const unsigned* p){
  unsigned v;
  asm volatile("global_load_dword %0, %1, off sc0 sc1\n\ts_waitcnt vmcnt(0)"
               : "=v"(v) : "v"(p) : "memory");
  return v;
}
__device__ __forceinline__ void store_coh16(unsigned short* p, unsigned v){
  asm volatile("global_store_short %0, %1, off sc0 sc1" :: "v"(p), "v"(v) : "memory");
}
__device__ __forceinline__ void store_cohf(float* p, float v){
  asm volatile("global_store_dword %0, %1, off sc0 sc1" :: "v"(p), "v"(v) : "memory");
}
__device__ __forceinline__ void store_cohu(unsigned* p, unsigned v){
  asm volatile("global_store_dword %0, %1, off sc0 sc1" :: "v"(p), "v"(v) : "memory");
}

// ---- grid barrier: RMW-free flags + detector; gen sharded on 8 lines ------
__device__ __forceinline__ void gbar3(unsigned* barb, unsigned bi1, int nblk,
                                      bool det, int myblk){
  asm volatile("s_waitcnt vmcnt(0)" ::: "memory");
  __syncthreads();
  const int tid = threadIdx.x;
  if(tid == 0) store_cohu(barb + (size_t)myblk*16, bi1);
  if(det){
    if(tid < nblk){
      const unsigned* fp = barb + (size_t)tid*16;
      while(load_coh(fp) < bi1) __builtin_amdgcn_s_sleep(1);
    }
    __syncthreads();
    if(tid < 8) store_cohu(barb + 4096 + (size_t)tid*16, bi1);
  } else {
    if(tid == 0){
      const unsigned* gp = barb + 4096 + (size_t)(myblk & 7)*16;
      while(load_coh(gp) < bi1) __builtin_amdgcn_s_sleep(1);
    }
  }
  __syncthreads();
}

__global__ void k_barinit(unsigned* bar){
  int i = blockIdx.x*256 + threadIdx.x;
  if(i < 16384) bar[i] = 0u;
}

// ------------- embedding gather -> bf16 ------------------------------------
__global__ void k_gather(const int* __restrict__ ids, const float* __restrict__ emb,
                         unsigned short* __restrict__ out){
  const int row = blockIdx.x;
  const int id  = ids[row];
  float4 v = *(const float4*)(emb + (size_t)id*E_ + threadIdx.x*4);
  ushort4 o;
  o.x = f2bf(v.x); o.y = f2bf(v.y); o.z = f2bf(v.z); o.w = f2bf(v.w);
  *(ushort4*)(out + (size_t)row*E_ + threadIdx.x*4) = o;
}

// ------------- transpose+convert(+permute)(+swizzle), 32x32 tile -----------
__device__ __forceinline__ void tcvt_dev(const float* __restrict__ in,
    unsigned short* __restrict__ out, int N, int Hp, int Kfull, int koff, int swz,
    int bx, int by, float (*tile)[33]){
  const int n0 = bx*32, k0 = by*32;
  const int x = threadIdx.x & 31, y = threadIdx.x >> 5;
  __syncthreads();
  #pragma unroll
  for(int i=0;i<4;i++){
    int k = y + i*8;
    tile[k][x] = in[(size_t)(k0+k)*N + n0 + x];
  }
  __syncthreads();
  #pragma unroll
  for(int i=0;i<4;i++){
    int nl = y + i*8;
    int n  = n0 + nl;
    int p  = Hp ? ((n % Hp)*4 + n / Hp) : n;
    int kk = koff + k0 + x;
    size_t idx;
    if(swz){
      int k2 = kk*2;
      int slot = ((k2>>4)&7) ^ (p&7);
      idx = (size_t)p*Kfull + (((k2 & ~127) | (slot<<4) | (k2 & 15)) >> 1);
    } else {
      idx = (size_t)p*Kfull + kk;
    }
    out[idx] = f2bf(tile[x][nl]);
  }
}

__global__ __launch_bounds__(256)
void k_tcvt(const float* __restrict__ in, unsigned short* __restrict__ out,
            int N, int Hp, int Kfull, int koff, int swz){
  __shared__ float tile[32][33];
  tcvt_dev(in, out, N, Hp, Kfull, koff, swz, blockIdx.x, blockIdx.y, tile);
}

// ------------- WIDE transpose-cvt: 32 k-rows x 256 n-cols per call ---------
__device__ __forceinline__ void tcvtw_dev(const float* __restrict__ in,
    unsigned short* __restrict__ out, int N, int K, int bx, int by,
    float (*tile)[257]){
  const int tid = threadIdx.x;
  const int n0 = bx*256, k0 = by*32;
  const int row = tid >> 3, nc = (tid & 7)*32;
  __syncthreads();
  #pragma unroll
  for(int j=0;j<8;j++){
    float4 v = *(const float4*)(in + (size_t)(k0+row)*N + n0 + nc + j*4);
    *(float4*)&tile[row][nc + j*4] = v;
  }
  __syncthreads();
  __align__(16) unsigned short vals[32];
  #pragma unroll
  for(int k=0;k<32;k++) vals[k] = f2bf(tile[k][tid]);
  unsigned short* op = out + (size_t)(n0+tid)*K + k0;
  #pragma unroll
  for(int j=0;j<4;j++)
    *(uint4*)(op + j*8) = *(const uint4*)&vals[j*8];
}

// ------------- bias permute -------------------------------------------------
__global__ void k_bpack(const float* __restrict__ b, float* __restrict__ out, int H, int N){
  int p = blockIdx.x*256 + threadIdx.x;
  if(p < N) out[p] = b[(p&3)*H + (p>>2)];
}

// ------------- init states --------------------------------------------------
__global__ void k_init1(const float* __restrict__ init_state,
                        unsigned short* h0i, float* c0i, unsigned short* h1i, float* c1i){
  int i = blockIdx.x*256 + threadIdx.x;
  if(i >= B_*H_) return;
  float v0 = init_state[i];
  float v1 = init_state[B_*H_ + i];
  h0i[i] = f2bf(v0); c0i[i] = v0;
  h1i[i] = f2bf(v1); c1i[i] = v1;
}

// h0seq1/h1seq1 are T-MAJOR ([t*B+b]) — final row at t=63.
__global__ void k_init2(const float* __restrict__ init_state,
                        const unsigned short* __restrict__ h0seq1,
                        const unsigned short* __restrict__ h1seq1,
                        const float* __restrict__ c0f1, const float* __restrict__ c1f1,
                        unsigned short* h20i, unsigned short* h21i,
                        float* c20i, float* c21i){
  const int l = blockIdx.y;
  int i = blockIdx.x*256 + threadIdx.x;
  if(i >= B_*2*H_) return;
  const int r = i >> 10, j = i & 1023;
  unsigned short* ho = l ? h21i : h20i;
  float* co = l ? c21i : c20i;
  if(j < H_){
    float v = init_state[(size_t)l*B_*H_ + r*H_ + j];
    ho[i] = f2bf(v); co[i] = v;
  } else {
    const unsigned short* hs = l ? h1seq1 : h0seq1;
    const float* cf = l ? c1f1 : c0f1;
    ho[i] = hs[(size_t)((T_-1)*B_ + r)*H_ + (j - H_)];
    co[i] = cf[r*H_ + (j - H_)];
  }
}

// ------------- MFMA GEMM tile (B pre-transposed bf16); optional row remap --
__device__ __forceinline__ void mm_tile(const unsigned short* __restrict__ A,
    const unsigned short* __restrict__ Bt, const float* __restrict__ bias,
    float* __restrict__ C, int N, int K, int bm, int bn,
    unsigned short* As, unsigned short* Bs, int remap){
  const int tid = threadIdx.x;
  const int lane = tid & 63, w = tid >> 6;
  const int wm = (w>>1)*64, wn = (w&1)*64;
  const int l15 = lane & 15, kg = lane >> 4;
  f32x4 acc[4][4] = {};
  for(int k0=0; k0<K; k0+=64){
    __syncthreads();
    #pragma unroll
    for(int ch=0; ch<4; ch++){
      int off = ch*4096 + tid*16;
      int row = off >> 7;
      int s   = ((off >> 4) & 7) ^ (row & 7);
      __builtin_amdgcn_global_load_lds(
        (const __attribute__((address_space(1))) unsigned int*)(A + (size_t)(bm+row)*K + k0 + s*8),
        (__attribute__((address_space(3))) unsigned int*)((char*)As + off), 16, 0, 0);
    }
    #pragma unroll
    for(int ch=0; ch<4; ch++){
      int off = ch*4096 + tid*16;
      int row = off >> 7;
      int s   = ((off >> 4) & 7) ^ (row & 7);
      __builtin_amdgcn_global_load_lds(
        (const __attribute__((address_space(1))) unsigned int*)(Bt + (size_t)(bn+row)*K + k0 + s*8),
        (__attribute__((address_space(3))) unsigned int*)((char*)Bs + off), 16, 0, 0);
    }
    __syncthreads();
    #pragma unroll
    for(int q=0;q<2;q++){
      s16x8 af[4], bf[4];
      #pragma unroll
      for(int mt=0;mt<4;mt++){
        int row = wm + mt*16 + l15;
        int s = (q*4 + kg) ^ (row & 7);
        af[mt] = *(const s16x8*)(As + row*64 + s*8);
      }
      #pragma unroll
      for(int nt=0;nt<4;nt++){
        int row = wn + nt*16 + l15;
        int s = (q*4 + kg) ^ (row & 7);
        bf[nt] = *(const s16x8*)(Bs + row*64 + s*8);
      }
      #pragma unroll
      for(int mt=0;mt<4;mt++)
        #pragma unroll
        for(int nt=0;nt<4;nt++)
          acc[mt][nt] = __builtin_amdgcn_mfma_f32_16x16x32_bf16(af[mt], bf[nt], acc[mt][nt], 0, 0, 0);
    }
  }
  #pragma unroll
  for(int mt=0;mt<4;mt++){
    #pragma unroll
    for(int nt=0;nt<4;nt++){
      int col = bn + wn + nt*16 + l15;
      float bv = bias ? bias[col] : 0.f;
      #pragma unroll
      for(int e=0;e<4;e++){
        int row = bm + wm + mt*16 + kg*4 + e;
        int orow = remap ? ((row & 15)*T_ + (row >> 4)) : row;
        C[(size_t)orow*N + col] = acc[mt][nt][e] + bv;
      }
    }
  }
}

// ------------- standalone MFMA GEMM kernel (bm0 = row offset) --------------
template<int BF32>
__global__ __launch_bounds__(256)
void k_mm(const unsigned short* __restrict__ A, const void* __restrict__ Bsrc,
          const float* __restrict__ bias, float* __restrict__ C,
          int M, int N, int K, int remap, int bm0){
  __shared__ __align__(16) unsigned short As[128*64];
  __shared__ __align__(16) unsigned short Bs[128*64];
  if(!BF32){
    mm_tile(A, (const unsigned short*)Bsrc, bias, C, N, K,
            bm0 + blockIdx.y*128, blockIdx.x*128, As, Bs, remap);
    return;
  }
  const int tid = threadIdx.x;
  const int lane = tid & 63, w = tid >> 6;
  const int wm = (w>>1)*64, wn = (w&1)*64;
  const int bm = bm0 + blockIdx.y*128, bn = blockIdx.x*128;
  const int l15 = lane & 15, kg = lane >> 4;
  f32x4 acc[4][4] = {};
  for(int k0=0; k0<K; k0+=64){
    __syncthreads();
    #pragma unroll
    for(int ch=0; ch<4; ch++){
      int off = ch*4096 + tid*16;
      int row = off >> 7;
      int s   = ((off >> 4) & 7) ^ (row & 7);
      __builtin_amdgcn_global_load_lds(
        (const __attribute__((address_space(1))) unsigned int*)(A + (size_t)(bm+row)*K + k0 + s*8),
        (__attribute__((address_space(3))) unsigned int*)((char*)As + off), 16, 0, 0);
    }
    {
      const float* Bf = (const float*)Bsrc;
      #pragma unroll
      for(int i=0;i<8;i++){
        int kl = (tid>>5) + i*8;
        int nl = (tid&31)*4;
        float4 v = *(const float4*)(Bf + (size_t)(k0+kl)*N + bn + nl);
        int slot = kl >> 3, kb = kl & 7;
        float vv[4] = {v.x, v.y, v.z, v.w};
        #pragma unroll
        for(int jj=0;jj<4;jj++){
          int n = nl + jj;
          Bs[n*64 + ((slot ^ (n&7))*8) + kb] = f2bf(vv[jj]);
        }
      }
    }
    __syncthreads();
    #pragma unroll
    for(int q=0;q<2;q++){
      s16x8 af[4], bf[4];
      #pragma unroll
      for(int mt=0;mt<4;mt++){
        int row = wm + mt*16 + l15;
        int s = (q*4 + kg) ^ (row & 7);
        af[mt] = *(const s16x8*)(As + row*64 + s*8);
      }
      #pragma unroll
      for(int nt=0;nt<4;nt++){
        int row = wn + nt*16 + l15;
        int s = (q*4 + kg) ^ (row & 7);
        bf[nt] = *(const s16x8*)(Bs + row*64 + s*8);
      }
      #pragma unroll
      for(int mt=0;mt<4;mt++)
        #pragma unroll
        for(int nt=0;nt<4;nt++)
          acc[mt][nt] = __builtin_amdgcn_mfma_f32_16x16x32_bf16(af[mt], bf[nt], acc[mt][nt], 0, 0, 0);
    }
  }
  #pragma unroll
  for(int mt=0;mt<4;mt++){
    #pragma unroll
    for(int nt=0;nt<4;nt++){
      int col = bn + wn + nt*16 + l15;
      float bv = bias ? bias[col] : 0.f;
      #pragma unroll
      for(int e=0;e<4;e++){
        int row = bm + wm + mt*16 + kg*4 + e;
        int orow = remap ? ((row & 15)*T_ + (row >> 4)) : row;
        C[(size_t)orow*N + col] = acc[mt][nt][e] + bv;
      }
    }
  }
}

// ------------- persistent 2-layer LSTM body; TB=1 -> t-major hseq ----------
template<int C, int K, int LAYER, int HU, int TB>
__device__ __forceinline__ void rnn_body(
    unsigned short* __restrict__ Uld, float* __restrict__ zp,
    const unsigned short* __restrict__ Uslice,
    const float* __restrict__ xw0, const float* __restrict__ bpk,
    const unsigned short* __restrict__ h0init, const unsigned short* __restrict__ h1init,
    const float* __restrict__ cinit,
    unsigned short* __restrict__ h0seq, unsigned short* __restrict__ h1seq,
    float* __restrict__ cfin, unsigned* bar, int cb, int nblk, bool det, int myblk)
{
  constexpr int KW = K/4, KS = KW/32, FR = C/16, UB = C/4;
  constexpr int K2 = K*2;
  constexpr int ITEMS = 16*UB;
  const int tid = threadIdx.x;
  const int lane = tid & 63, w = tid >> 6;
  const int l15 = lane & 15, kg = lane >> 4;

  constexpr int CP = (C*K2)/4096;
  #pragma unroll
  for(int i=0;i<CP;i++){
    __builtin_amdgcn_global_load_lds(
      (const __attribute__((address_space(1))) unsigned int*)((const char*)Uslice + i*4096 + tid*16),
      (__attribute__((address_space(3))) unsigned int*)((char*)Uld + i*4096 + tid*16), 16, 0, 0);
  }
  const int base_p = cb*C;
  const int base_u = cb*UB;
  float4 bvr = make_float4(0.f,0.f,0.f,0.f);
  int er = 0, eu = 0;
  if(tid < ITEMS){ er = tid / UB; eu = tid - er*UB; bvr = *(const float4*)(bpk + base_p + eu*4); }
  float creg = 0.f;
  unsigned short* hseqW = LAYER ? h1seq : h0seq;

  int cbyte[FR], cx[FR];
  #pragma unroll
  for(int f=0;f<FR;f++){ int c = f*16 + l15; cbyte[f] = c*K2; cx[f] = (c&7)<<4; }

  __syncthreads();

  for(int it = 0; it <= T_; ++it){
    const bool active = LAYER ? (it >= 1) : (it < T_);
    const int t = LAYER ? it-1 : it;
    if(active){
      const unsigned short* asrc;
      if constexpr(LAYER == 0){
        asrc = (t == 0) ? (h0init + l15*HU)
             : (h0seq + ((size_t)(TB ? ((t-1)*B_ + l15) : (l15*T_ + (t-1))))*HU);
      } else {
        if(w < 2){
          asrc = h0seq + ((size_t)(TB ? (t*B_ + l15) : (l15*T_ + t)))*HU;
        } else {
          asrc = ((t == 0) ? (h1init + l15*HU)
               : (h1seq + ((size_t)(TB ? ((t-1)*B_ + l15) : (l15*T_ + (t-1))))*HU)) - HU;
        }
      }
      f32x4 acc[FR];
      #pragma unroll
      for(int f=0;f<FR;f++) acc[f] = (f32x4){0.f,0.f,0.f,0.f};
      #pragma unroll
      for(int s=0;s<KS;s++){
        const int kel = w*KW + s*32 + kg*8;
        s16x8 a = *(const s16x8*)(asrc + kel);
        const int kb  = kel*2;
        const int kch = kb & ~127;
        const int ksl = (kb >> 4) & 7;
        #pragma unroll
        for(int f=0;f<FR;f++){
          const int ad = cbyte[f] + kch + ((ksl<<4) ^ cx[f]);
          s16x8 b = *(const s16x8*)((const char*)Uld + ad);
          acc[f] = __builtin_amdgcn_mfma_f32_16x16x32_bf16(a, b, acc[f], 0, 0, 0);
        }
      }
      #pragma unroll
      for(int f=0;f<FR;f++)
        #pragma unroll
        for(int e=0;e<4;e++)
          zp[(w*16 + kg*4 + e)*68 + f*16 + l15] = acc[f][e];
    }
    __syncthreads();
    if(active && tid < ITEMS){
      float4 z0 = *(const float4*)(zp + (     er)*68 + eu*4);
      float4 z1 = *(const float4*)(zp + (16 + er)*68 + eu*4);
      float4 z2 = *(const float4*)(zp + (32 + er)*68 + eu*4);
      float4 z3 = *(const float4*)(zp + (48 + er)*68 + eu*4);
      float si = z0.x+z1.x+z2.x+z3.x + bvr.x;
      float sf = z0.y+z1.y+z2.y+z3.y + bvr.y;
      float sg = z0.z+z1.z+z2.z+z3.z + bvr.z;
      float so = z0.w+z1.w+z2.w+z3.w + bvr.w;
      if constexpr(LAYER == 0){
        float4 xv = *(const float4*)(xw0 + ((size_t)(er*T_ + t))*(4*HU) + base_p + eu*4);
        si += xv.x; sf += xv.y; sg += xv.z; so += xv.w;
      }
      float cin = (t == 0) ? cinit[er*HU + base_u + eu] : creg;
      float c2 = sigm(sf)*cin + sigm(si)*tanhf(sg);
      float h2 = sigm(so)*tanhf(c2);
      creg = c2;
      size_t hrow = TB ? ((size_t)(t*B_ + er)) : ((size_t)(er*T_ + t));
      store_coh16(&hseqW[hrow*HU + base_u + eu], (unsigned)f2bf(h2));
      if(t == T_-1) store_cohf(&cfin[er*HU + base_u + eu], c2);
    }
    if(it < T_) gbar3(bar, (unsigned)(it+1), nblk, det, myblk);
  }
  asm volatile("s_waitcnt vmcnt(0)" ::: "memory");
  __syncthreads();
  if(tid == 0) store_cohu(bar + (size_t)myblk*16, (unsigned)(T_+1));
}

// ------------- mega kernel 1: RNN1 + role-split spares ---------------------
// prep-role (96): wpT1w -> fence1 -> prep+wpT2w -> fence2 -> xw2
// proj1-role (96): wait fence1 -> proj1 8 t-groups gated on RNN1 L1 flags
__global__ __launch_bounds__(256, 1)
void k_rnn1m(const unsigned short* __restrict__ Ut0, const unsigned short* __restrict__ WU1,
    const float* __restrict__ xw0, const float* __restrict__ bpk0, const float* __restrict__ bpk1,
    const unsigned short* __restrict__ h0init, const unsigned short* __restrict__ h1init,
    const float* __restrict__ c0init, const float* __restrict__ c1init,
    unsigned short* __restrict__ h0seq, unsigned short* __restrict__ h1seq,
    float* __restrict__ c0fin, float* __restrict__ c1fin, unsigned* bar,
    const int* __restrict__ ids2, const float* __restrict__ emb, unsigned short* __restrict__ ebuf2,
    const float* __restrict__ b2_0, const float* __restrict__ b2_1,
    float* __restrict__ bpk20, float* __restrict__ bpk21,
    const float* __restrict__ U2_0, unsigned short* __restrict__ ut0_2,
    const float* __restrict__ W2_0, unsigned short* __restrict__ wtmp2,
    const float* __restrict__ W2_1, const float* __restrict__ U2_1, unsigned short* __restrict__ wu1_2,
    const float* __restrict__ Wp1, unsigned short* __restrict__ wpT1,
    const float* __restrict__ Wp2, unsigned short* __restrict__ wpT2,
    const float* __restrict__ bp1, float* __restrict__ out1,
    float* __restrict__ xw2buf, int wide)
{
  constexpr int HU = 512, C0 = 64, C1 = 64;
  constexpr int NB0 = 4*HU/C0;         // 32
  constexpr int NRNN = NB0 + 4*HU/C1;  // 64
  constexpr int NP = 96;               // prep-role blocks
  constexpr int NJ = 96;               // proj1-role blocks
  __shared__ __align__(16) unsigned short Uld[65536];
  __shared__ __align__(16) float zred[64*68];
  const int blk = blockIdx.x;
  const int tid = threadIdx.x;
  if(blk < NB0){
    rnn_body<C0, HU, 0, HU, 1>(Uld, zred, Ut0 + (size_t)blk*C0*HU, xw0, bpk0,
        h0init, h1init, c0init, h0seq, h1seq, c0fin, bar, blk, NRNN, blk==0, blk);
  } else if(blk < NRNN){
    rnn_body<C1, 2*HU, 1, HU, 1>(Uld, zred, WU1 + (size_t)(blk-NB0)*C1*2*HU, nullptr, bpk1,
        h0init, h1init, c1init, h0seq, h1seq, c1fin, bar, blk-NB0, NRNN, false, blk);
  } else if(blk < NRNN + NP){
    // ================= prep role =================
    const int q = blk - NRNN;          // 0..95
    float (*tile)[33]   = (float(*)[33])Uld;
    float (*tile2)[257] = (float(*)[257])Uld;
    unsigned short* As = Uld;
    unsigned short* Bs = Uld + 8192;
    // phase 0: wpT1 wide cvt FIRST (unblocks proj1 role)
    if(wide){
      for(int j = q; j < 2000; j += NP)
        tcvtw_dev(Wp1, wpT1, 32000, 512, j%125, j/125, tile2);
    }
    __syncthreads();
    __threadfence();
    if(tid == 0)
      __hip_atomic_fetch_add(bar + 5136, 1u, __ATOMIC_RELAXED, __HIP_MEMORY_SCOPE_AGENT);
    // phase 1: remaining prep (+ wpT2 wide)
    const int J0 = 512, J1 = J0+32, J2 = J1+4096, J3 = J2+2048, J4 = J3+4096, J5 = J4+4096;
    const int J6 = wide ? (J5 + 4000) : J5;
    for(int j = q; j < J6; j += NP){
      if(j < J0){
        int row = j*2 + (tid>>7);
        int id = ids2[row];
        float4 v = *(const float4*)(emb + (size_t)id*E_ + (tid&127)*4);
        ushort4 o; o.x=f2bf(v.x); o.y=f2bf(v.y); o.z=f2bf(v.z); o.w=f2bf(v.w);
        *(ushort4*)(ebuf2 + (size_t)row*E_ + (tid&127)*4) = o;
      } else if(j < J1){
        int jj = j - J0;
        const float* b = (jj < 16) ? b2_0 : b2_1;
        float* o = (jj < 16) ? bpk20 : bpk21;
        int p = (jj & 15)*256 + tid;
        o[p] = b[(p&3)*1024 + (p>>2)];
      } else if(j < J2){
        int r = j - J1; tcvt_dev(U2_0, ut0_2, 4096, 1024, 1024, 0, 1, r%128, r/128, tile);
      } else if(j < J3){
        int r = j - J2; tcvt_dev(W2_0, wtmp2, 4096, 1024, 512, 0, 0, r%128, r/128, tile);
      } else if(j < J4){
        int r = j - J3; tcvt_dev(W2_1, wu1_2, 4096, 1024, 2048, 0, 1, r%128, r/128, tile);
      } else if(j < J5){
        int r = j - J4; tcvt_dev(U2_1, wu1_2, 4096, 1024, 2048, 1024, 1, r%128, r/128, tile);
      } else {
        int r = j - J5; tcvtw_dev(Wp2, wpT2, 32000, 1024, r%125, r/125, tile2);
      }
    }
    __syncthreads();
    __threadfence();
    if(tid == 0)
      __hip_atomic_fetch_add(bar + 5152, 1u, __ATOMIC_RELAXED, __HIP_MEMORY_SCOPE_AGENT);
    if(tid == 0){
      while(load_coh(bar + 5152) < (unsigned)NP) __builtin_amdgcn_s_sleep(8);
    }
    __syncthreads();
    // phase 2: xw2 = ebuf2 @ wtmp2 (hidden; wide2 only)
    if(xw2buf){
      for(int t2 = q; t2 < 256; t2 += NP)
        mm_tile(ebuf2, wtmp2, nullptr, xw2buf, 4096, 512, (t2>>5)*128, (t2&31)*128, As, Bs, 0);
    }
  } else {
    // ================= proj1 role =================
    if(!wide) return;
    const int q2 = blk - NRNN - NP;    // 0..95
    unsigned short* As = Uld;
    unsigned short* Bs = Uld + 8192;
    volatile int* rdy = (volatile int*)((char*)Uld + 128000);
    if(tid == 0){
      while(load_coh(bar + 5136) < (unsigned)NP) __builtin_amdgcn_s_sleep(8);
    }
    __syncthreads();
    for(int g = 0; g < 8; ++g){
      const unsigned req = 8u*(unsigned)g + 9u;
      for(;;){
        if(tid == 0) *rdy = 1;
        __syncthreads();
        if(tid < 32){
          if(load_coh(bar + (size_t)(NB0 + tid)*16) < req) *rdy = 0;
        }
        __syncthreads();
        if(*rdy) break;
        __builtin_amdgcn_s_sleep(16);
      }
      for(int n = q2; n < 250; n += NJ)
        mm_tile(h1seq, wpT1, bp1, out1, V_, 512, g*128, n*128, As, Bs, 1);
    }
  }
}

// ------------- pure RNN2 kernel (grid 192) ---------------------------------
template<int HU, int C0, int C1>
__global__ __launch_bounds__(256, 1)
void k_rnn(const unsigned short* __restrict__ Ut0, const unsigned short* __restrict__ WU1,
           const float* __restrict__ xw0, const float* __restrict__ bpk0, const float* __restrict__ bpk1,
           const unsigned short* __restrict__ h0init, const unsigned short* __restrict__ h1init,
           const float* __restrict__ c0init, const float* __restrict__ c1init,
           unsigned short* __restrict__ h0seq, unsigned short* __restrict__ h1seq,
           float* __restrict__ c0fin, float* __restrict__ c1fin, unsigned* bar)
{
  constexpr int NB0 = 4*HU/C0;
  constexpr int UMAXE = (C0*HU > C1*2*HU) ? C0*HU : C1*2*HU;
  __shared__ __align__(16) unsigned short Uld[UMAXE];
  __shared__ __align__(16) float zred[64*68];
  const int nblk = gridDim.x;
  const bool det = (blockIdx.x == 0);
  const int blk = blockIdx.x;
  if(blk < NB0)
    rnn_body<C0, HU, 0, HU, 1>(Uld, zred, Ut0 + (size_t)blk*C0*HU, xw0, bpk0,
                               h0init, h1init, c0init, h0seq, h1seq, c0fin, bar, blk, nblk, det, blk);
  else
    rnn_body<C1, 2*HU, 1, HU, 1>(Uld, zred, WU1 + (size_t)(blk-NB0)*C1*2*HU, nullptr, bpk1,
                               h0init, h1init, c1init, h0seq, h1seq, c1fin, bar, blk-NB0, nblk, det, blk);
}

// ---------------------------------------------------------------------------
extern "C" void kernel_launch(void* const* d_in, const int* in_sizes, int n_in,
                              void* d_out, int out_size, void* d_ws, size_t ws_size,
                              hipStream_t stream){
  const int*   ids1 = (const int*)d_in[0];
  const int*   ids2 = (const int*)d_in[1];
  const float* init = (const float*)d_in[2];
  const float* emb  = (const float*)d_in[3];
  const float* W1_0 = (const float*)d_in[4];
  const float* U1_0 = (const float*)d_in[5];
  const float* b1_0 = (const float*)d_in[6];
  const float* W1_1 = (const float*)d_in[7];
  const float* U1_1 = (const float*)d_in[8];
  const float* b1_1 = (const float*)d_in[9];
  const float* W2_0 = (const float*)d_in[10];
  const float* U2_0 = (const float*)d_in[11];
  const float* b2_0 = (const float*)d_in[12];
  const float* W2_1 = (const float*)d_in[13];
  const float* U2_1 = (const float*)d_in[14];
  const float* b2_1 = (const float*)d_in[15];
  const float* Wp1  = (const float*)d_in[16];
  const float* bp1  = (const float*)d_in[17];
  const float* Wp2  = (const float*)d_in[18];
  const float* bp2  = (const float*)d_in[19];
  float* out1 = (float*)d_out;
  float* out2 = out1 + (size_t)B_*T_*V_;

  char* base = (char*)d_ws;
  float*          xw    = (float*)(base);                           // 16 MB
  unsigned short* ut0_1 = (unsigned short*)(base + (16u<<20));      // 2 MB
  unsigned short* wu1_1 = (unsigned short*)(base + (18u<<20));      // 4 MB
  unsigned short* ut0_2 = (unsigned short*)(base + (22u<<20));      // 8 MB
  unsigned short* wu1_2 = (unsigned short*)(base + (30u<<20));      // 16 MB
  unsigned short* wtmp  = (unsigned short*)(base + (46u<<20));      // 4 MB
  unsigned short* ebuf  = (unsigned short*)(base + (50u<<20));      // 1 MB
  unsigned short* h0s1  = (unsigned short*)(base + (51u<<20));      // 1 MB  [t*B+b]
  unsigned short* h1s1  = (unsigned short*)(base + (52u<<20));      // 1 MB  [t*B+b]
  unsigned short* h0s2  = (unsigned short*)(base + (53u<<20));      // 2 MB  [t*B+b]
  unsigned short* h1s2  = (unsigned short*)(base + (55u<<20));      // 2 MB  [t*B+b]
  char* M = base + (57u<<20);
  unsigned short* h0i1 = (unsigned short*)(M);
  unsigned short* h1i1 = (unsigned short*)(M + 16384);
  float* c0i1 = (float*)(M + 32768);
  float* c1i1 = (float*)(M + 65536);
  unsigned short* h2i0 = (unsigned short*)(M + 98304);
  unsigned short* h2i1 = (unsigned short*)(M + 131072);
  float* c2i0 = (float*)(M + 163840);
  float* c2i1 = (float*)(M + 229376);
  float* c0f1 = (float*)(M + 294912);
  float* c1f1 = (float*)(M + 327680);
  float* c0f2 = (float*)(M + 360448);
  float* c1f2 = (float*)(M + 425984);
  float* bpk10 = (float*)(M + 491520);
  float* bpk11 = (float*)(M + 499712);
  float* bpk20 = (float*)(M + 507904);
  float* bpk21 = (float*)(M + 524288);
  unsigned* bar1 = (unsigned*)(M + 540672);            // 32 KB
  unsigned* bar2 = (unsigned*)(M + 540672 + 32768);    // 32 KB
  unsigned short* wpT1 = (unsigned short*)(base + (58u<<20));   // 31.25 MiB
  unsigned short* wpT2 = (unsigned short*)(base + (90u<<20));   // 62.5 MiB
  float*          xw2  = (float*)(base + (153u<<20));           // 16 MiB
  const size_t NEED_W  = ((size_t)90u<<20) + (size_t)V_*1024*2;
  const size_t NEED_W2 = ((size_t)169u<<20);
  const bool wide  = ws_size >= NEED_W;
  const bool wide2 = ws_size >= NEED_W2;
  float* xw2p = (wide && wide2) ? xw2 : xw;

  k_barinit<<<dim3(64), dim3(256), 0, stream>>>(bar1);

  // ===== RNN1 prep =====
  k_init1<<<dim3(32), dim3(256), 0, stream>>>(init, h0i1, c0i1, h1i1, c1i1);
  k_gather<<<dim3(B_*T_), dim3(128), 0, stream>>>(ids1, emb, ebuf);
  k_tcvt<<<dim3(64, 16), dim3(256), 0, stream>>>(U1_0, ut0_1, 2048, 512, 512, 0, 1);
  k_tcvt<<<dim3(64, 16), dim3(256), 0, stream>>>(W1_0, wtmp,  2048, 512, 512, 0, 0);
  k_tcvt<<<dim3(64, 16), dim3(256), 0, stream>>>(W1_1, wu1_1, 2048, 512, 1024, 0, 1);
  k_tcvt<<<dim3(64, 16), dim3(256), 0, stream>>>(U1_1, wu1_1, 2048, 512, 1024, 512, 1);
  k_bpack<<<dim3(8),  dim3(256), 0, stream>>>(b1_0, bpk10, 512, 2048);
  k_bpack<<<dim3(8),  dim3(256), 0, stream>>>(b1_1, bpk11, 512, 2048);
  k_mm<0><<<dim3(16, 8), dim3(256), 0, stream>>>(ebuf, wtmp, nullptr, xw, 1024, 2048, 512, 0, 0);

  // ===== RNN1 + role-split spares =====
  k_rnn1m<<<dim3(256), dim3(256), 0, stream>>>(ut0_1, wu1_1, xw, bpk10, bpk11,
      h0i1, h1i1, c0i1, c1i1, h0s1, h1s1, c0f1, c1f1, bar1,
      ids2, emb, ebuf, b2_0, b2_1, bpk20, bpk21,
      U2_0, ut0_2, W2_0, wtmp, W2_1, U2_1, wu1_2,
      Wp1, wpT1, Wp2, wpT2, bp1, out1,
      (wide && wide2) ? xw2 : nullptr, (int)wide);

  if(!wide){
    k_mm<1><<<dim3(250, 8), dim3(256), 0, stream>>>(h1s1, Wp1, bp1, out1, 1024, V_, 512, 1, 0);
  }
  if(!wide || !wide2){
    // serial xw2 (overwrites xw after RNN1 done — safe)
    k_mm<0><<<dim3(32, 8), dim3(256), 0, stream>>>(ebuf, wtmp, nullptr, xw, 1024, 4096, 512, 0, 0);
  }
  k_init2<<<dim3(64, 2), dim3(256), 0, stream>>>(init, h0s1, h1s1, c0f1, c1f1,
                                                 h2i0, h2i1, c2i0, c2i1);

  // ===== pure RNN2 =====
  k_rnn<1024, 64, 32><<<dim3(192), dim3(256), 0, stream>>>(ut0_2, wu1_2, xw2p, bpk20, bpk21,
      h2i0, h2i1, c2i0, c2i1, h0s2, h1s2, c0f2, c1f2, bar2);

  // ===== projection 2 (full, serial) =====
  if(wide){
    k_mm<0><<<dim3(250, 8), dim3(256), 0, stream>>>(h1s2, wpT2, bp2, out2, 1024, V_, 1024, 1, 0);
  } else {
    k_mm<1><<<dim3(250, 8), dim3(256), 0, stream>>>(h1s2, Wp2, bp2, out2, 1024, V_, 1024, 1, 0);
  }
}

// Round 16
// 869.238 us; speedup vs baseline: 1.1897x; 1.0033x over previous
//
#include <hip/hip_runtime.h>
#include <hip/hip_bf16.h>

#define B_ 16
#define T_ 64
#define E_ 512
#define H_ 512
#define V_ 32000

typedef __attribute__((ext_vector_type(4))) float f32x4;
typedef __attribute__((ext_vector_type(8))) short s16x8;

__device__ __forceinline__ float sigm(float x){ return 1.0f/(1.0f + __expf(-x)); }

__device__ __forceinline__ unsigned short f2bf(float x){
  unsigned int u = __float_as_uint(x);
  return (unsigned short)((u + 0x7FFFu + ((u>>16)&1u)) >> 16);
}

// ---- coherence-point ops (no cache-wide writeback/invalidate anywhere) ----
__device__ __forceinline__ unsigned load_coh(const unsigned* p){
  unsigned v;
  asm volatile("global_load_dword %0, %1, off sc0 sc1\n\ts_waitcnt vmcnt(0)"
               : "=v"(v) : "v"(p) : "memory");
  return v;
}
__device__ __forceinline__ void store_coh16(unsigned short* p, unsigned v){
  asm volatile("global_store_short %0, %1, off sc0 sc1" :: "v"(p), "v"(v) : "memory");
}
__device__ __forceinline__ void store_cohf(float* p, float v){
  asm volatile("global_store_dword %0, %1, off sc0 sc1" :: "v"(p), "v"(v) : "memory");
}
__device__ __forceinline__ void store_cohu(unsigned* p, unsigned v){
  asm volatile("global_store_dword %0, %1, off sc0 sc1" :: "v"(p), "v"(v) : "memory");
}

__global__ void k_barinit(unsigned* bar){
  int i = blockIdx.x*256 + threadIdx.x;
  if(i < 16384) bar[i] = 0u;
}

// ------------- embedding gather -> bf16 ------------------------------------
__global__ void k_gather(const int* __restrict__ ids, const float* __restrict__ emb,
                         unsigned short* __restrict__ out){
  const int row = blockIdx.x;
  const int id  = ids[row];
  float4 v = *(const float4*)(emb + (size_t)id*E_ + threadIdx.x*4);
  ushort4 o;
  o.x = f2bf(v.x); o.y = f2bf(v.y); o.z = f2bf(v.z); o.w = f2bf(v.w);
  *(ushort4*)(out + (size_t)row*E_ + threadIdx.x*4) = o;
}

// ------------- transpose+convert(+permute)(+swizzle), 32x32 tile -----------
__device__ __forceinline__ void tcvt_dev(const float* __restrict__ in,
    unsigned short* __restrict__ out, int N, int Hp, int Kfull, int koff, int swz,
    int bx, int by, float (*tile)[33]){
  const int n0 = bx*32, k0 = by*32;
  const int x = threadIdx.x & 31, y = threadIdx.x >> 5;
  __syncthreads();
  #pragma unroll
  for(int i=0;i<4;i++){
    int k = y + i*8;
    tile[k][x] = in[(size_t)(k0+k)*N + n0 + x];
  }
  __syncthreads();
  #pragma unroll
  for(int i=0;i<4;i++){
    int nl = y + i*8;
    int n  = n0 + nl;
    int p  = Hp ? ((n % Hp)*4 + n / Hp) : n;
    int kk = koff + k0 + x;
    size_t idx;
    if(swz){
      int k2 = kk*2;
      int slot = ((k2>>4)&7) ^ (p&7);
      idx = (size_t)p*Kfull + (((k2 & ~127) | (slot<<4) | (k2 & 15)) >> 1);
    } else {
      idx = (size_t)p*Kfull + kk;
    }
    out[idx] = f2bf(tile[x][nl]);
  }
}

__global__ __launch_bounds__(256)
void k_tcvt(const float* __restrict__ in, unsigned short* __restrict__ out,
            int N, int Hp, int Kfull, int koff, int swz){
  __shared__ float tile[32][33];
  tcvt_dev(in, out, N, Hp, Kfull, koff, swz, blockIdx.x, blockIdx.y, tile);
}

// ------------- WIDE transpose-cvt: 32 k-rows x 256 n-cols per call ---------
__device__ __forceinline__ void tcvtw_dev(const float* __restrict__ in,
    unsigned short* __restrict__ out, int N, int K, int bx, int by,
    float (*tile)[257]){
  const int tid = threadIdx.x;
  const int n0 = bx*256, k0 = by*32;
  const int row = tid >> 3, nc = (tid & 7)*32;
  __syncthreads();
  #pragma unroll
  for(int j=0;j<8;j++){
    float4 v = *(const float4*)(in + (size_t)(k0+row)*N + n0 + nc + j*4);
    *(float4*)&tile[row][nc + j*4] = v;
  }
  __syncthreads();
  __align__(16) unsigned short vals[32];
  #pragma unroll
  for(int k=0;k<32;k++) vals[k] = f2bf(tile[k][tid]);
  unsigned short* op = out + (size_t)(n0+tid)*K + k0;
  #pragma unroll
  for(int j=0;j<4;j++)
    *(uint4*)(op + j*8) = *(const uint4*)&vals[j*8];
}

// ------------- bias permute -------------------------------------------------
__global__ void k_bpack(const float* __restrict__ b, float* __restrict__ out, int H, int N){
  int p = blockIdx.x*256 + threadIdx.x;
  if(p < N) out[p] = b[(p&3)*H + (p>>2)];
}

// ------------- init states --------------------------------------------------
__global__ void k_init1(const float* __restrict__ init_state,
                        unsigned short* h0i, float* c0i, unsigned short* h1i, float* c1i){
  int i = blockIdx.x*256 + threadIdx.x;
  if(i >= B_*H_) return;
  float v0 = init_state[i];
  float v1 = init_state[B_*H_ + i];
  h0i[i] = f2bf(v0); c0i[i] = v0;
  h1i[i] = f2bf(v1); c1i[i] = v1;
}

// h0seq1/h1seq1 are T-MAJOR ([t*B+b]) — final row at t=63.
__global__ void k_init2(const float* __restrict__ init_state,
                        const unsigned short* __restrict__ h0seq1,
                        const unsigned short* __restrict__ h1seq1,
                        const float* __restrict__ c0f1, const float* __restrict__ c1f1,
                        unsigned short* h20i, unsigned short* h21i,
                        float* c20i, float* c21i){
  const int l = blockIdx.y;
  int i = blockIdx.x*256 + threadIdx.x;
  if(i >= B_*2*H_) return;
  const int r = i >> 10, j = i & 1023;
  unsigned short* ho = l ? h21i : h20i;
  float* co = l ? c21i : c20i;
  if(j < H_){
    float v = init_state[(size_t)l*B_*H_ + r*H_ + j];
    ho[i] = f2bf(v); co[i] = v;
  } else {
    const unsigned short* hs = l ? h1seq1 : h0seq1;
    const float* cf = l ? c1f1 : c0f1;
    ho[i] = hs[(size_t)((T_-1)*B_ + r)*H_ + (j - H_)];
    co[i] = cf[r*H_ + (j - H_)];
  }
}

// ------------- MFMA GEMM tile (B pre-transposed bf16); optional row remap --
__device__ __forceinline__ void mm_tile(const unsigned short* __restrict__ A,
    const unsigned short* __restrict__ Bt, const float* __restrict__ bias,
    float* __restrict__ C, int N, int K, int bm, int bn,
    unsigned short* As, unsigned short* Bs, int remap){
  const int tid = threadIdx.x;
  const int lane = tid & 63, w = tid >> 6;
  const int wm = (w>>1)*64, wn = (w&1)*64;
  const int l15 = lane & 15, kg = lane >> 4;
  f32x4 acc[4][4] = {};
  for(int k0=0; k0<K; k0+=64){
    __syncthreads();
    #pragma unroll
    for(int ch=0; ch<4; ch++){
      int off = ch*4096 + tid*16;
      int row = off >> 7;
      int s   = ((off >> 4) & 7) ^ (row & 7);
      __builtin_amdgcn_global_load_lds(
        (const __attribute__((address_space(1))) unsigned int*)(A + (size_t)(bm+row)*K + k0 + s*8),
        (__attribute__((address_space(3))) unsigned int*)((char*)As + off), 16, 0, 0);
    }
    #pragma unroll
    for(int ch=0; ch<4; ch++){
      int off = ch*4096 + tid*16;
      int row = off >> 7;
      int s   = ((off >> 4) & 7) ^ (row & 7);
      __builtin_amdgcn_global_load_lds(
        (const __attribute__((address_space(1))) unsigned int*)(Bt + (size_t)(bn+row)*K + k0 + s*8),
        (__attribute__((address_space(3))) unsigned int*)((char*)Bs + off), 16, 0, 0);
    }
    __syncthreads();
    #pragma unroll
    for(int q=0;q<2;q++){
      s16x8 af[4], bf[4];
      #pragma unroll
      for(int mt=0;mt<4;mt++){
        int row = wm + mt*16 + l15;
        int s = (q*4 + kg) ^ (row & 7);
        af[mt] = *(const s16x8*)(As + row*64 + s*8);
      }
      #pragma unroll
      for(int nt=0;nt<4;nt++){
        int row = wn + nt*16 + l15;
        int s = (q*4 + kg) ^ (row & 7);
        bf[nt] = *(const s16x8*)(Bs + row*64 + s*8);
      }
      #pragma unroll
      for(int mt=0;mt<4;mt++)
        #pragma unroll
        for(int nt=0;nt<4;nt++)
          acc[mt][nt] = __builtin_amdgcn_mfma_f32_16x16x32_bf16(af[mt], bf[nt], acc[mt][nt], 0, 0, 0);
    }
  }
  #pragma unroll
  for(int mt=0;mt<4;mt++){
    #pragma unroll
    for(int nt=0;nt<4;nt++){
      int col = bn + wn + nt*16 + l15;
      float bv = bias ? bias[col] : 0.f;
      #pragma unroll
      for(int e=0;e<4;e++){
        int row = bm + wm + mt*16 + kg*4 + e;
        int orow = remap ? ((row & 15)*T_ + (row >> 4)) : row;
        C[(size_t)orow*N + col] = acc[mt][nt][e] + bv;
      }
    }
  }
}

// ------------- standalone MFMA GEMM kernel (bm0 = row offset) --------------
template<int BF32>
__global__ __launch_bounds__(256)
void k_mm(const unsigned short* __restrict__ A, const void* __restrict__ Bsrc,
          const float* __restrict__ bias, float* __restrict__ C,
          int M, int N, int K, int remap, int bm0){
  __shared__ __align__(16) unsigned short As[128*64];
  __shared__ __align__(16) unsigned short Bs[128*64];
  if(!BF32){
    mm_tile(A, (const unsigned short*)Bsrc, bias, C, N, K,
            bm0 + blockIdx.y*128, blockIdx.x*128, As, Bs, remap);
    return;
  }
  const int tid = threadIdx.x;
  const int lane = tid & 63, w = tid >> 6;
  const int wm = (w>>1)*64, wn = (w&1)*64;
  const int bm = bm0 + blockIdx.y*128, bn = blockIdx.x*128;
  const int l15 = lane & 15, kg = lane >> 4;
  f32x4 acc[4][4] = {};
  for(int k0=0; k0<K; k0+=64){
    __syncthreads();
    #pragma unroll
    for(int ch=0; ch<4; ch++){
      int off = ch*4096 + tid*16;
      int row = off >> 7;
      int s   = ((off >> 4) & 7) ^ (row & 7);
      __builtin_amdgcn_global_load_lds(
        (const __attribute__((address_space(1))) unsigned int*)(A + (size_t)(bm+row)*K + k0 + s*8),
        (__attribute__((address_space(3))) unsigned int*)((char*)As + off), 16, 0, 0);
    }
    {
      const float* Bf = (const float*)Bsrc;
      #pragma unroll
      for(int i=0;i<8;i++){
        int kl = (tid>>5) + i*8;
        int nl = (tid&31)*4;
        float4 v = *(const float4*)(Bf + (size_t)(k0+kl)*N + bn + nl);
        int slot = kl >> 3, kb = kl & 7;
        float vv[4] = {v.x, v.y, v.z, v.w};
        #pragma unroll
        for(int jj=0;jj<4;jj++){
          int n = nl + jj;
          Bs[n*64 + ((slot ^ (n&7))*8) + kb] = f2bf(vv[jj]);
        }
      }
    }
    __syncthreads();
    #pragma unroll
    for(int q=0;q<2;q++){
      s16x8 af[4], bf[4];
      #pragma unroll
      for(int mt=0;mt<4;mt++){
        int row = wm + mt*16 + l15;
        int s = (q*4 + kg) ^ (row & 7);
        af[mt] = *(const s16x8*)(As + row*64 + s*8);
      }
      #pragma unroll
      for(int nt=0;nt<4;nt++){
        int row = wn + nt*16 + l15;
        int s = (q*4 + kg) ^ (row & 7);
        bf[nt] = *(const s16x8*)(Bs + row*64 + s*8);
      }
      #pragma unroll
      for(int mt=0;mt<4;mt++)
        #pragma unroll
        for(int nt=0;nt<4;nt++)
          acc[mt][nt] = __builtin_amdgcn_mfma_f32_16x16x32_bf16(af[mt], bf[nt], acc[mt][nt], 0, 0, 0);
    }
  }
  #pragma unroll
  for(int mt=0;mt<4;mt++){
    #pragma unroll
    for(int nt=0;nt<4;nt++){
      int col = bn + wn + nt*16 + l15;
      float bv = bias ? bias[col] : 0.f;
      #pragma unroll
      for(int e=0;e<4;e++){
        int row = bm + wm + mt*16 + kg*4 + e;
        int orow = remap ? ((row & 15)*T_ + (row >> 4)) : row;
        C[(size_t)orow*N + col] = acc[mt][nt][e] + bv;
      }
    }
  }
}

// ------------- persistent 2-layer LSTM body; direct dataflow sync ----------
// Wait at loop TOP: L0 waits L0-flags >= it; L1 waits L0-flags AND L1-flags >= it.
// Publish flag = it+1 at loop BOTTOM (after stores drained). No detector/gen.
template<int C, int K, int LAYER, int HU, int TB>
__device__ __forceinline__ void rnn_body(
    unsigned short* __restrict__ Uld, float* __restrict__ zp,
    const unsigned short* __restrict__ Uslice,
    const float* __restrict__ xw0, const float* __restrict__ bpk,
    const unsigned short* __restrict__ h0init, const unsigned short* __restrict__ h1init,
    const float* __restrict__ cinit,
    unsigned short* __restrict__ h0seq, unsigned short* __restrict__ h1seq,
    float* __restrict__ cfin, unsigned* bar, int cb, int nb0, int nrnn, int myblk)
{
  constexpr int KW = K/4, KS = KW/32, FR = C/16, UB = C/4;
  constexpr int K2 = K*2;
  constexpr int ITEMS = 16*UB;
  const int tid = threadIdx.x;
  const int lane = tid & 63, w = tid >> 6;
  const int l15 = lane & 15, kg = lane >> 4;

  constexpr int CP = (C*K2)/4096;
  #pragma unroll
  for(int i=0;i<CP;i++){
    __builtin_amdgcn_global_load_lds(
      (const __attribute__((address_space(1))) unsigned int*)((const char*)Uslice + i*4096 + tid*16),
      (__attribute__((address_space(3))) unsigned int*)((char*)Uld + i*4096 + tid*16), 16, 0, 0);
  }
  const int base_p = cb*C;
  const int base_u = cb*UB;
  float4 bvr = make_float4(0.f,0.f,0.f,0.f);
  int er = 0, eu = 0;
  if(tid < ITEMS){ er = tid / UB; eu = tid - er*UB; bvr = *(const float4*)(bpk + base_p + eu*4); }
  float creg = 0.f;
  unsigned short* hseqW = LAYER ? h1seq : h0seq;

  int cbyte[FR], cx[FR];
  #pragma unroll
  for(int f=0;f<FR;f++){ int c = f*16 + l15; cbyte[f] = c*K2; cx[f] = (c&7)<<4; }

  __syncthreads();

  for(int it = 0; it <= T_; ++it){
    // ---- direct dataflow wait (wave 0 polls producer flags) ----
    if(it > 0){
      if(tid < 64){
        const int fmax = (LAYER == 0) ? nb0 : nrnn;
        for(int f = tid; f < fmax; f += 64){
          const unsigned* fp = bar + (size_t)f*16;
          if(load_coh(fp) < (unsigned)it){
            while(load_coh(fp) < (unsigned)it) __builtin_amdgcn_s_sleep(4);
          }
        }
      }
      __syncthreads();
    }
    const bool active = LAYER ? (it >= 1) : (it < T_);
    const int t = LAYER ? it-1 : it;
    if(active){
      const unsigned short* asrc;
      if constexpr(LAYER == 0){
        asrc = (t == 0) ? (h0init + l15*HU)
             : (h0seq + ((size_t)(TB ? ((t-1)*B_ + l15) : (l15*T_ + (t-1))))*HU);
      } else {
        if(w < 2){
          asrc = h0seq + ((size_t)(TB ? (t*B_ + l15) : (l15*T_ + t)))*HU;
        } else {
          asrc = ((t == 0) ? (h1init + l15*HU)
               : (h1seq + ((size_t)(TB ? ((t-1)*B_ + l15) : (l15*T_ + (t-1))))*HU)) - HU;
        }
      }
      f32x4 acc[FR];
      #pragma unroll
      for(int f=0;f<FR;f++) acc[f] = (f32x4){0.f,0.f,0.f,0.f};
      #pragma unroll
      for(int s=0;s<KS;s++){
        const int kel = w*KW + s*32 + kg*8;
        s16x8 a = *(const s16x8*)(asrc + kel);
        const int kb  = kel*2;
        const int kch = kb & ~127;
        const int ksl = (kb >> 4) & 7;
        #pragma unroll
        for(int f=0;f<FR;f++){
          const int ad = cbyte[f] + kch + ((ksl<<4) ^ cx[f]);
          s16x8 b = *(const s16x8*)((const char*)Uld + ad);
          acc[f] = __builtin_amdgcn_mfma_f32_16x16x32_bf16(a, b, acc[f], 0, 0, 0);
        }
      }
      #pragma unroll
      for(int f=0;f<FR;f++)
        #pragma unroll
        for(int e=0;e<4;e++)
          zp[(w*16 + kg*4 + e)*68 + f*16 + l15] = acc[f][e];
    }
    __syncthreads();
    if(active && tid < ITEMS){
      float4 z0 = *(const float4*)(zp + (     er)*68 + eu*4);
      float4 z1 = *(const float4*)(zp + (16 + er)*68 + eu*4);
      float4 z2 = *(const float4*)(zp + (32 + er)*68 + eu*4);
      float4 z3 = *(const float4*)(zp + (48 + er)*68 + eu*4);
      float si = z0.x+z1.x+z2.x+z3.x + bvr.x;
      float sf = z0.y+z1.y+z2.y+z3.y + bvr.y;
      float sg = z0.z+z1.z+z2.z+z3.z + bvr.z;
      float so = z0.w+z1.w+z2.w+z3.w + bvr.w;
      if constexpr(LAYER == 0){
        float4 xv = *(const float4*)(xw0 + ((size_t)(er*T_ + t))*(4*HU) + base_p + eu*4);
        si += xv.x; sf += xv.y; sg += xv.z; so += xv.w;
      }
      float cin = (t == 0) ? cinit[er*HU + base_u + eu] : creg;
      float c2 = sigm(sf)*cin + sigm(si)*tanhf(sg);
      float h2 = sigm(so)*tanhf(c2);
      creg = c2;
      size_t hrow = TB ? ((size_t)(t*B_ + er)) : ((size_t)(er*T_ + t));
      store_coh16(&hseqW[hrow*HU + base_u + eu], (unsigned)f2bf(h2));
      if(t == T_-1) store_cohf(&cfin[er*HU + base_u + eu], c2);
    }
    // ---- publish: drain stores, then flag = it+1 ----
    asm volatile("s_waitcnt vmcnt(0)" ::: "memory");
    __syncthreads();
    if(tid == 0) store_cohu(bar + (size_t)myblk*16, (unsigned)(it+1));
  }
}

// ------------- mega kernel 1: RNN1 + role-split spares ---------------------
__global__ __launch_bounds__(256, 1)
void k_rnn1m(const unsigned short* __restrict__ Ut0, const unsigned short* __restrict__ WU1,
    const float* __restrict__ xw0, const float* __restrict__ bpk0, const float* __restrict__ bpk1,
    const unsigned short* __restrict__ h0init, const unsigned short* __restrict__ h1init,
    const float* __restrict__ c0init, const float* __restrict__ c1init,
    unsigned short* __restrict__ h0seq, unsigned short* __restrict__ h1seq,
    float* __restrict__ c0fin, float* __restrict__ c1fin, unsigned* bar,
    const int* __restrict__ ids2, const float* __restrict__ emb, unsigned short* __restrict__ ebuf2,
    const float* __restrict__ b2_0, const float* __restrict__ b2_1,
    float* __restrict__ bpk20, float* __restrict__ bpk21,
    const float* __restrict__ U2_0, unsigned short* __restrict__ ut0_2,
    const float* __restrict__ W2_0, unsigned short* __restrict__ wtmp2,
    const float* __restrict__ W2_1, const float* __restrict__ U2_1, unsigned short* __restrict__ wu1_2,
    const float* __restrict__ Wp1, unsigned short* __restrict__ wpT1,
    const float* __restrict__ Wp2, unsigned short* __restrict__ wpT2,
    const float* __restrict__ bp1, float* __restrict__ out1,
    float* __restrict__ xw2buf, int wide)
{
  constexpr int HU = 512, C0 = 64, C1 = 64;
  constexpr int NB0 = 4*HU/C0;         // 32
  constexpr int NRNN = NB0 + 4*HU/C1;  // 64
  constexpr int NP = 96;               // prep-role blocks
  constexpr int NJ = 96;               // proj1-role blocks
  __shared__ __align__(16) unsigned short Uld[65536];
  __shared__ __align__(16) float zred[64*68];
  const int blk = blockIdx.x;
  const int tid = threadIdx.x;
  if(blk < NB0){
    rnn_body<C0, HU, 0, HU, 1>(Uld, zred, Ut0 + (size_t)blk*C0*HU, xw0, bpk0,
        h0init, h1init, c0init, h0seq, h1seq, c0fin, bar, blk, NB0, NRNN, blk);
  } else if(blk < NRNN){
    rnn_body<C1, 2*HU, 1, HU, 1>(Uld, zred, WU1 + (size_t)(blk-NB0)*C1*2*HU, nullptr, bpk1,
        h0init, h1init, c1init, h0seq, h1seq, c1fin, bar, blk-NB0, NB0, NRNN, blk);
  } else if(blk < NRNN + NP){
    // ================= prep role =================
    const int q = blk - NRNN;          // 0..95
    float (*tile)[33]   = (float(*)[33])Uld;
    float (*tile2)[257] = (float(*)[257])Uld;
    unsigned short* As = Uld;
    unsigned short* Bs = Uld + 8192;
    // phase 0: wpT1 wide cvt FIRST (unblocks proj1 role)
    if(wide){
      for(int j = q; j < 2000; j += NP)
        tcvtw_dev(Wp1, wpT1, 32000, 512, j%125, j/125, tile2);
    }
    __syncthreads();
    __threadfence();
    if(tid == 0)
      __hip_atomic_fetch_add(bar + 5136, 1u, __ATOMIC_RELAXED, __HIP_MEMORY_SCOPE_AGENT);
    // phase 1: remaining prep (+ wpT2 wide)
    const int J0 = 512, J1 = J0+32, J2 = J1+4096, J3 = J2+2048, J4 = J3+4096, J5 = J4+4096;
    const int J6 = wide ? (J5 + 4000) : J5;
    for(int j = q; j < J6; j += NP){
      if(j < J0){
        int row = j*2 + (tid>>7);
        int id = ids2[row];
        float4 v = *(const float4*)(emb + (size_t)id*E_ + (tid&127)*4);
        ushort4 o; o.x=f2bf(v.x); o.y=f2bf(v.y); o.z=f2bf(v.z); o.w=f2bf(v.w);
        *(ushort4*)(ebuf2 + (size_t)row*E_ + (tid&127)*4) = o;
      } else if(j < J1){
        int jj = j - J0;
        const float* b = (jj < 16) ? b2_0 : b2_1;
        float* o = (jj < 16) ? bpk20 : bpk21;
        int p = (jj & 15)*256 + tid;
        o[p] = b[(p&3)*1024 + (p>>2)];
      } else if(j < J2){
        int r = j - J1; tcvt_dev(U2_0, ut0_2, 4096, 1024, 1024, 0, 1, r%128, r/128, tile);
      } else if(j < J3){
        int r = j - J2; tcvt_dev(W2_0, wtmp2, 4096, 1024, 512, 0, 0, r%128, r/128, tile);
      } else if(j < J4){
        int r = j - J3; tcvt_dev(W2_1, wu1_2, 4096, 1024, 2048, 0, 1, r%128, r/128, tile);
      } else if(j < J5){
        int r = j - J4; tcvt_dev(U2_1, wu1_2, 4096, 1024, 2048, 1024, 1, r%128, r/128, tile);
      } else {
        int r = j - J5; tcvtw_dev(Wp2, wpT2, 32000, 1024, r%125, r/125, tile2);
      }
    }
    __syncthreads();
    __threadfence();
    if(tid == 0)
      __hip_atomic_fetch_add(bar + 5152, 1u, __ATOMIC_RELAXED, __HIP_MEMORY_SCOPE_AGENT);
    if(tid == 0){
      while(load_coh(bar + 5152) < (unsigned)NP) __builtin_amdgcn_s_sleep(8);
    }
    __syncthreads();
    // phase 2: xw2 = ebuf2 @ wtmp2 (hidden; wide2 only)
    if(xw2buf){
      for(int t2 = q; t2 < 256; t2 += NP)
        mm_tile(ebuf2, wtmp2, nullptr, xw2buf, 4096, 512, (t2>>5)*128, (t2&31)*128, As, Bs, 0);
    }
  } else {
    // ================= proj1 role =================
    if(!wide) return;
    const int q2 = blk - NRNN - NP;    // 0..95
    unsigned short* As = Uld;
    unsigned short* Bs = Uld + 8192;
    volatile int* rdy = (volatile int*)((char*)Uld + 128000);
    if(tid == 0){
      while(load_coh(bar + 5136) < (unsigned)NP) __builtin_amdgcn_s_sleep(8);
    }
    __syncthreads();
    for(int g = 0; g < 8; ++g){
      const unsigned req = 8u*(unsigned)g + 9u;
      for(;;){
        if(tid == 0) *rdy = 1;
        __syncthreads();
        if(tid < 32){
          if(load_coh(bar + (size_t)(NB0 + tid)*16) < req) *rdy = 0;
        }
        __syncthreads();
        if(*rdy) break;
        __builtin_amdgcn_s_sleep(16);
      }
      for(int n = q2; n < 250; n += NJ)
        mm_tile(h1seq, wpT1, bp1, out1, V_, 512, g*128, n*128, As, Bs, 1);
    }
  }
}

// ------------- pure RNN2 kernel (grid 192) ---------------------------------
template<int HU, int C0, int C1>
__global__ __launch_bounds__(256, 1)
void k_rnn(const unsigned short* __restrict__ Ut0, const unsigned short* __restrict__ WU1,
           const float* __restrict__ xw0, const float* __restrict__ bpk0, const float* __restrict__ bpk1,
           const unsigned short* __restrict__ h0init, const unsigned short* __restrict__ h1init,
           const float* __restrict__ c0init, const float* __restrict__ c1init,
           unsigned short* __restrict__ h0seq, unsigned short* __restrict__ h1seq,
           float* __restrict__ c0fin, float* __restrict__ c1fin, unsigned* bar)
{
  constexpr int NB0 = 4*HU/C0;
  constexpr int NRNN = NB0 + 4*HU/C1;
  constexpr int UMAXE = (C0*HU > C1*2*HU) ? C0*HU : C1*2*HU;
  __shared__ __align__(16) unsigned short Uld[UMAXE];
  __shared__ __align__(16) float zred[64*68];
  const int blk = blockIdx.x;
  if(blk < NB0)
    rnn_body<C0, HU, 0, HU, 1>(Uld, zred, Ut0 + (size_t)blk*C0*HU, xw0, bpk0,
                               h0init, h1init, c0init, h0seq, h1seq, c0fin, bar, blk, NB0, NRNN, blk);
  else
    rnn_body<C1, 2*HU, 1, HU, 1>(Uld, zred, WU1 + (size_t)(blk-NB0)*C1*2*HU, nullptr, bpk1,
                               h0init, h1init, c1init, h0seq, h1seq, c1fin, bar, blk-NB0, NB0, NRNN, blk);
}

// ---------------------------------------------------------------------------
extern "C" void kernel_launch(void* const* d_in, const int* in_sizes, int n_in,
                              void* d_out, int out_size, void* d_ws, size_t ws_size,
                              hipStream_t stream){
  const int*   ids1 = (const int*)d_in[0];
  const int*   ids2 = (const int*)d_in[1];
  const float* init = (const float*)d_in[2];
  const float* emb  = (const float*)d_in[3];
  const float* W1_0 = (const float*)d_in[4];
  const float* U1_0 = (const float*)d_in[5];
  const float* b1_0 = (const float*)d_in[6];
  const float* W1_1 = (const float*)d_in[7];
  const float* U1_1 = (const float*)d_in[8];
  const float* b1_1 = (const float*)d_in[9];
  const float* W2_0 = (const float*)d_in[10];
  const float* U2_0 = (const float*)d_in[11];
  const float* b2_0 = (const float*)d_in[12];
  const float* W2_1 = (const float*)d_in[13];
  const float* U2_1 = (const float*)d_in[14];
  const float* b2_1 = (const float*)d_in[15];
  const float* Wp1  = (const float*)d_in[16];
  const float* bp1  = (const float*)d_in[17];
  const float* Wp2  = (const float*)d_in[18];
  const float* bp2  = (const float*)d_in[19];
  float* out1 = (float*)d_out;
  float* out2 = out1 + (size_t)B_*T_*V_;

  char* base = (char*)d_ws;
  float*          xw    = (float*)(base);                           // 16 MB
  unsigned short* ut0_1 = (unsigned short*)(base + (16u<<20));      // 2 MB
  unsigned short* wu1_1 = (unsigned short*)(base + (18u<<20));      // 4 MB
  unsigned short* ut0_2 = (unsigned short*)(base + (22u<<20));      // 8 MB
  unsigned short* wu1_2 = (unsigned short*)(base + (30u<<20));      // 16 MB
  unsigned short* wtmp  = (unsigned short*)(base + (46u<<20));      // 4 MB
  unsigned short* ebuf  = (unsigned short*)(base + (50u<<20));      // 1 MB
  unsigned short* h0s1  = (unsigned short*)(base + (51u<<20));      // 1 MB  [t*B+b]
  unsigned short* h1s1  = (unsigned short*)(base + (52u<<20));      // 1 MB  [t*B+b]
  unsigned short* h0s2  = (unsigned short*)(base + (53u<<20));      // 2 MB  [t*B+b]
  unsigned short* h1s2  = (unsigned short*)(base + (55u<<20));      // 2 MB  [t*B+b]
  char* M = base + (57u<<20);
  unsigned short* h0i1 = (unsigned short*)(M);
  unsigned short* h1i1 = (unsigned short*)(M + 16384);
  float* c0i1 = (float*)(M + 32768);
  float* c1i1 = (float*)(M + 65536);
  unsigned short* h2i0 = (unsigned short*)(M + 98304);
  unsigned short* h2i1 = (unsigned short*)(M + 131072);
  float* c2i0 = (float*)(M + 163840);
  float* c2i1 = (float*)(M + 229376);
  float* c0f1 = (float*)(M + 294912);
  float* c1f1 = (float*)(M + 327680);
  float* c0f2 = (float*)(M + 360448);
  float* c1f2 = (float*)(M + 425984);
  float* bpk10 = (float*)(M + 491520);
  float* bpk11 = (float*)(M + 499712);
  float* bpk20 = (float*)(M + 507904);
  float* bpk21 = (float*)(M + 524288);
  unsigned* bar1 = (unsigned*)(M + 540672);            // 32 KB
  unsigned* bar2 = (unsigned*)(M + 540672 + 32768);    // 32 KB
  unsigned short* wpT1 = (unsigned short*)(base + (58u<<20));   // 31.25 MiB
  unsigned short* wpT2 = (unsigned short*)(base + (90u<<20));   // 62.5 MiB
  float*          xw2  = (float*)(base + (153u<<20));           // 16 MiB
  const size_t NEED_W  = ((size_t)90u<<20) + (size_t)V_*1024*2;
  const size_t NEED_W2 = ((size_t)169u<<20);
  const bool wide  = ws_size >= NEED_W;
  const bool wide2 = ws_size >= NEED_W2;
  float* xw2p = (wide && wide2) ? xw2 : xw;

  k_barinit<<<dim3(64), dim3(256), 0, stream>>>(bar1);

  // ===== RNN1 prep =====
  k_init1<<<dim3(32), dim3(256), 0, stream>>>(init, h0i1, c0i1, h1i1, c1i1);
  k_gather<<<dim3(B_*T_), dim3(128), 0, stream>>>(ids1, emb, ebuf);
  k_tcvt<<<dim3(64, 16), dim3(256), 0, stream>>>(U1_0, ut0_1, 2048, 512, 512, 0, 1);
  k_tcvt<<<dim3(64, 16), dim3(256), 0, stream>>>(W1_0, wtmp,  2048, 512, 512, 0, 0);
  k_tcvt<<<dim3(64, 16), dim3(256), 0, stream>>>(W1_1, wu1_1, 2048, 512, 1024, 0, 1);
  k_tcvt<<<dim3(64, 16), dim3(256), 0, stream>>>(U1_1, wu1_1, 2048, 512, 1024, 512, 1);
  k_bpack<<<dim3(8),  dim3(256), 0, stream>>>(b1_0, bpk10, 512, 2048);
  k_bpack<<<dim3(8),  dim3(256), 0, stream>>>(b1_1, bpk11, 512, 2048);
  k_mm<0><<<dim3(16, 8), dim3(256), 0, stream>>>(ebuf, wtmp, nullptr, xw, 1024, 2048, 512, 0, 0);

  // ===== RNN1 + role-split spares =====
  k_rnn1m<<<dim3(256), dim3(256), 0, stream>>>(ut0_1, wu1_1, xw, bpk10, bpk11,
      h0i1, h1i1, c0i1, c1i1, h0s1, h1s1, c0f1, c1f1, bar1,
      ids2, emb, ebuf, b2_0, b2_1, bpk20, bpk21,
      U2_0, ut0_2, W2_0, wtmp, W2_1, U2_1, wu1_2,
      Wp1, wpT1, Wp2, wpT2, bp1, out1,
      (wide && wide2) ? xw2 : nullptr, (int)wide);

  if(!wide){
    k_mm<1><<<dim3(250, 8), dim3(256), 0, stream>>>(h1s1, Wp1, bp1, out1, 1024, V_, 512, 1, 0);
  }
  if(!wide || !wide2){
    // serial xw2 (overwrites xw after RNN1 done — safe)
    k_mm<0><<<dim3(32, 8), dim3(256), 0, stream>>>(ebuf, wtmp, nullptr, xw, 1024, 4096, 512, 0, 0);
  }
  k_init2<<<dim3(64, 2), dim3(256), 0, stream>>>(init, h0s1, h1s1, c0f1, c1f1,
                                                 h2i0, h2i1, c2i0, c2i1);

  // ===== pure RNN2 =====
  k_rnn<1024, 64, 32><<<dim3(192), dim3(256), 0, stream>>>(ut0_2, wu1_2, xw2p, bpk20, bpk21,
      h2i0, h2i1, c2i0, c2i1, h0s2, h1s2, c0f2, c1f2, bar2);

  // ===== projection 2 (full, serial) =====
  if(wide){
    k_mm<0><<<dim3(250, 8), dim3(256), 0, stream>>>(h1s2, wpT2, bp2, out2, 1024, V_, 1024, 1, 0);
  } else {
    k_mm<1><<<dim3(250, 8), dim3(256), 0, stream>>>(h1s2, Wp2, bp2, out2, 1024, V_, 1024, 1, 0);
  }
}